// Round 1
// baseline (11361.762 us; speedup 1.0000x reference)
//
#include <hip/hip_runtime.h>

#define F 256          // feature dim (both in and hid)
#define BM 64
#define BN 64
#define BK 16

// Tiled fp32 GEMM: C[M,F] = A[M,F] * B[F,F]  (B = one relation's W, row-major)
__global__ __launch_bounds__(256) void gemm_f32(const float* __restrict__ A,
                                                const float* __restrict__ B,
                                                float* __restrict__ C, int M) {
    __shared__ float As[BK][BM + 4];   // +4 pad keeps float4 alignment, breaks bank stride
    __shared__ float Bs[BK][BN];

    const int tid = threadIdx.x;
    const int row0 = blockIdx.x * BM;
    const int col0 = blockIdx.y * BN;

    const int tr = tid / 16;          // 0..15 thread row
    const int tc = tid % 16;          // 0..15 thread col

    // A-tile load mapping: 64 rows x 16 k; one float4 per thread
    const int a_r = tid / 4;          // 0..63
    const int a_c = (tid % 4) * 4;    // 0,4,8,12
    // B-tile load mapping: 16 k x 64 cols; one float4 per thread
    const int b_r = tid / 16;         // 0..15
    const int b_c = (tid % 16) * 4;   // 0..60

    float acc[4][4] = {};

    for (int k0 = 0; k0 < F; k0 += BK) {
        const int gr = row0 + a_r;
        float4 av = make_float4(0.f, 0.f, 0.f, 0.f);
        if (gr < M) av = *(const float4*)(A + (long long)gr * F + k0 + a_c);
        As[a_c + 0][a_r] = av.x;
        As[a_c + 1][a_r] = av.y;
        As[a_c + 2][a_r] = av.z;
        As[a_c + 3][a_r] = av.w;

        float4 bv = *(const float4*)(B + (long long)(k0 + b_r) * F + col0 + b_c);
        *(float4*)(&Bs[b_r][b_c]) = bv;

        __syncthreads();

#pragma unroll
        for (int kk = 0; kk < BK; ++kk) {
            float4 ar4 = *(const float4*)(&As[kk][tr * 4]);
            float4 br4 = *(const float4*)(&Bs[kk][tc * 4]);
            float ar[4] = {ar4.x, ar4.y, ar4.z, ar4.w};
            float br[4] = {br4.x, br4.y, br4.z, br4.w};
#pragma unroll
            for (int i = 0; i < 4; ++i)
#pragma unroll
                for (int j = 0; j < 4; ++j)
                    acc[i][j] = fmaf(ar[i], br[j], acc[i][j]);
        }
        __syncthreads();
    }

#pragma unroll
    for (int i = 0; i < 4; ++i) {
        const int gr = row0 + tr * 4 + i;
        if (gr < M) {
            float4 o = make_float4(acc[i][0], acc[i][1], acc[i][2], acc[i][3]);
            *(float4*)(C + (long long)gr * F + col0 + tc * 4) = o;
        }
    }
}

// Edge scatter: acc[dst] += h[src] * val.  One wave covers one edge's 256 feats
// (64 lanes x float4).  Atomic adds into acc.
__global__ __launch_bounds__(256) void scatter_kern(const float* __restrict__ h,
                                                    const int* __restrict__ src,
                                                    const int* __restrict__ dst,
                                                    const float* __restrict__ val,
                                                    float* __restrict__ acc,
                                                    long long total) {
    long long idx = (long long)blockIdx.x * blockDim.x + threadIdx.x;
    if (idx >= total) return;
    const int e = (int)(idx >> 6);
    const int q = ((int)idx & 63) * 4;
    const int s = src[e];
    const int d = dst[e];
    const float v = val[e];
    float4 hv = *(const float4*)(h + (long long)s * F + q);
    float* ap = acc + (long long)d * F + q;
    atomicAdd(ap + 0, hv.x * v);
    atomicAdd(ap + 1, hv.y * v);
    atomicAdd(ap + 2, hv.z * v);
    atomicAdd(ap + 3, hv.w * v);
}

// out = relu(acc + b)     (vectorized float4; out here becomes x1)
__global__ __launch_bounds__(256) void bias_relu_kern(const float* __restrict__ acc,
                                                      const float* __restrict__ b,
                                                      float* __restrict__ out,
                                                      long long n4) {
    long long i = (long long)blockIdx.x * blockDim.x + threadIdx.x;
    if (i >= n4) return;
    float4 a = ((const float4*)acc)[i];
    int col = (int)(i & 63);                 // F/4 = 64 float4 groups per row
    float4 bb = ((const float4*)b)[col];
    float4 o;
    o.x = fmaxf(a.x + bb.x, 0.f);
    o.y = fmaxf(a.y + bb.y, 0.f);
    o.z = fmaxf(a.z + bb.z, 0.f);
    o.w = fmaxf(a.w + bb.w, 0.f);
    ((float4*)out)[i] = o;
}

// x1out = relu(acc + b) + x1out   (reads x1 from d_out, writes final result)
__global__ __launch_bounds__(256) void final_kern(const float* __restrict__ acc,
                                                  const float* __restrict__ b,
                                                  float* __restrict__ x1out,
                                                  long long n4) {
    long long i = (long long)blockIdx.x * blockDim.x + threadIdx.x;
    if (i >= n4) return;
    float4 a = ((const float4*)acc)[i];
    float4 x1 = ((const float4*)x1out)[i];
    int col = (int)(i & 63);
    float4 bb = ((const float4*)b)[col];
    float4 o;
    o.x = fmaxf(a.x + bb.x, 0.f) + x1.x;
    o.y = fmaxf(a.y + bb.y, 0.f) + x1.y;
    o.z = fmaxf(a.z + bb.z, 0.f) + x1.z;
    o.w = fmaxf(a.w + bb.w, 0.f) + x1.w;
    ((float4*)x1out)[i] = o;
}

extern "C" void kernel_launch(void* const* d_in, const int* in_sizes, int n_in,
                              void* d_out, int out_size, void* d_ws, size_t ws_size,
                              hipStream_t stream) {
    const float* x    = (const float*)d_in[0];
    const int*   esrc = (const int*)  d_in[1];
    const int*   edst = (const int*)  d_in[2];
    const float* eval = (const float*)d_in[3];
    const float* W1   = (const float*)d_in[4];
    const float* b1   = (const float*)d_in[5];
    const float* W2   = (const float*)d_in[6];
    const float* b2   = (const float*)d_in[7];
    float* out = (float*)d_out;

    const int N = in_sizes[0] / F;
    const int R = in_sizes[4] / (F * F);
    const int E = in_sizes[1] / R;

    float* h   = (float*)d_ws;                 // [N, F]
    float* acc = h + (size_t)N * F;            // [N, F]

    dim3 ggrid((N + BM - 1) / BM, F / BN);
    const long long sc_total = (long long)E * (F / 4);
    const int sc_blocks = (int)((sc_total + 255) / 256);
    const long long n4 = (long long)N * (F / 4);
    const int eb = (int)((n4 + 255) / 256);

    // ---- layer 1 ----
    hipMemsetAsync(acc, 0, (size_t)N * F * sizeof(float), stream);
    for (int r = 0; r < R; ++r) {
        gemm_f32<<<ggrid, 256, 0, stream>>>(x, W1 + (size_t)r * F * F, h, N);
        scatter_kern<<<sc_blocks, 256, 0, stream>>>(h, esrc + (size_t)r * E,
                                                    edst + (size_t)r * E,
                                                    eval + (size_t)r * E, acc, sc_total);
    }
    bias_relu_kern<<<eb, 256, 0, stream>>>(acc, b1, out, n4);   // out = x1

    // ---- layer 2 ----
    hipMemsetAsync(acc, 0, (size_t)N * F * sizeof(float), stream);
    for (int r = 0; r < R; ++r) {
        gemm_f32<<<ggrid, 256, 0, stream>>>(out, W2 + (size_t)r * F * F, h, N);
        scatter_kern<<<sc_blocks, 256, 0, stream>>>(h, esrc + (size_t)r * E,
                                                    edst + (size_t)r * E,
                                                    eval + (size_t)r * E, acc, sc_total);
    }
    final_kern<<<eb, 256, 0, stream>>>(acc, b2, out, n4);       // out = relu(acc+b2) + x1
}

// Round 2
// 1338.989 us; speedup vs baseline: 8.4853x; 8.4853x over previous
//
#include <hip/hip_runtime.h>

#define F 256          // feature dim (in and hid)
#define BM 64
#define BN 64
#define BK 16
#define SCAN_T 256
#define SCAN_ELEMS 1024   // elements scanned per block (4 per thread)

// ---------------- GEMM: h[z] = A @ W[z], fp32, tiled ----------------
__global__ __launch_bounds__(256) void gemm_f32_batched(const float* __restrict__ A,
                                                        const float* __restrict__ W,
                                                        float* __restrict__ H, int M) {
    __shared__ float As[BK][BM + 4];
    __shared__ float Bs[BK][BN];

    const int tid = threadIdx.x;
    const int row0 = blockIdx.x * BM;
    const int col0 = blockIdx.y * BN;
    const int rel  = blockIdx.z;

    const float* B = W + (size_t)rel * F * F;
    float* C = H + (size_t)rel * M * F;

    const int tr = tid / 16;
    const int tc = tid % 16;
    const int a_r = tid / 4;
    const int a_c = (tid % 4) * 4;
    const int b_r = tid / 16;
    const int b_c = (tid % 16) * 4;

    float acc[4][4] = {};

    for (int k0 = 0; k0 < F; k0 += BK) {
        const int gr = row0 + a_r;
        float4 av = make_float4(0.f, 0.f, 0.f, 0.f);
        if (gr < M) av = *(const float4*)(A + (long long)gr * F + k0 + a_c);
        As[a_c + 0][a_r] = av.x;
        As[a_c + 1][a_r] = av.y;
        As[a_c + 2][a_r] = av.z;
        As[a_c + 3][a_r] = av.w;

        float4 bv = *(const float4*)(B + (long long)(k0 + b_r) * F + col0 + b_c);
        *(float4*)(&Bs[b_r][b_c]) = bv;

        __syncthreads();
#pragma unroll
        for (int kk = 0; kk < BK; ++kk) {
            float4 ar4 = *(const float4*)(&As[kk][tr * 4]);
            float4 br4 = *(const float4*)(&Bs[kk][tc * 4]);
            float ar[4] = {ar4.x, ar4.y, ar4.z, ar4.w};
            float br[4] = {br4.x, br4.y, br4.z, br4.w};
#pragma unroll
            for (int i = 0; i < 4; ++i)
#pragma unroll
                for (int j = 0; j < 4; ++j)
                    acc[i][j] = fmaf(ar[i], br[j], acc[i][j]);
        }
        __syncthreads();
    }

#pragma unroll
    for (int i = 0; i < 4; ++i) {
        const int gr = row0 + tr * 4 + i;
        if (gr < M) {
            float4 o = make_float4(acc[i][0], acc[i][1], acc[i][2], acc[i][3]);
            *(float4*)(C + (long long)gr * F + col0 + tc * 4) = o;
        }
    }
}

// ---------------- CSR build ----------------
// counts/row_ptr indexed by key = r*N + dst  (RN+1 ints; counts alias row_ptr)
__global__ __launch_bounds__(256) void count_kern(const int* __restrict__ edst,
                                                  int* __restrict__ counts,
                                                  int total, int E, int Nn) {
    int i = blockIdx.x * blockDim.x + threadIdx.x;
    if (i >= total) return;
    int r = i / E;
    atomicAdd(counts + r * Nn + edst[i], 1);
}

// block-local exclusive scan (in place), block totals out
__global__ __launch_bounds__(SCAN_T) void scan1_kern(int* __restrict__ data,
                                                     int* __restrict__ bsum, int n) {
    __shared__ int sh[SCAN_T];
    const int t = threadIdx.x;
    const int base = blockIdx.x * SCAN_ELEMS + t * 4;
    int v[4];
    int tsum = 0;
#pragma unroll
    for (int j = 0; j < 4; ++j) {
        v[j] = (base + j < n) ? data[base + j] : 0;
        tsum += v[j];
    }
    sh[t] = tsum;
    __syncthreads();
    for (int off = 1; off < SCAN_T; off <<= 1) {
        int x = (t >= off) ? sh[t - off] : 0;
        __syncthreads();
        sh[t] += x;
        __syncthreads();
    }
    if (t == SCAN_T - 1) bsum[blockIdx.x] = sh[t];
    int run = sh[t] - tsum;   // exclusive prefix of this thread's chunk
#pragma unroll
    for (int j = 0; j < 4; ++j) {
        if (base + j < n) data[base + j] = run;
        run += v[j];
    }
}

// single-block exclusive scan of block sums (nb <= 256)
__global__ __launch_bounds__(SCAN_T) void scan2_kern(int* __restrict__ bsum, int nb) {
    __shared__ int sh[SCAN_T];
    const int t = threadIdx.x;
    int val = (t < nb) ? bsum[t] : 0;
    sh[t] = val;
    __syncthreads();
    for (int off = 1; off < SCAN_T; off <<= 1) {
        int x = (t >= off) ? sh[t - off] : 0;
        __syncthreads();
        sh[t] += x;
        __syncthreads();
    }
    if (t < nb) bsum[t] = sh[t] - val;  // exclusive
}

// add block offsets; copy to cursor; set row_ptr[n] = total
__global__ __launch_bounds__(256) void scan3_kern(int* __restrict__ row_ptr,
                                                  const int* __restrict__ bsum,
                                                  int* __restrict__ cursor,
                                                  int n, int total) {
    int i = blockIdx.x * blockDim.x + threadIdx.x;
    if (i < n) {
        int v = row_ptr[i] + bsum[i >> 10];
        row_ptr[i] = v;
        cursor[i]  = v;
    } else if (i == n) {
        row_ptr[n] = total;
    }
}

__global__ __launch_bounds__(256) void fill_kern(const int* __restrict__ esrc,
                                                 const int* __restrict__ edst,
                                                 const float* __restrict__ eval,
                                                 int* __restrict__ cursor,
                                                 int2* __restrict__ epack,
                                                 int total, int E, int Nn) {
    int i = blockIdx.x * blockDim.x + threadIdx.x;
    if (i >= total) return;
    int r = i / E;
    int key = r * Nn + edst[i];
    int pos = atomicAdd(cursor + key, 1);
    epack[pos] = make_int2(esrc[i], __float_as_int(eval[i]));
}

// ---------------- Aggregate: one wave per dst row ----------------
// out[d] = relu( sum_r sum_e val * h[r][src] + bias )  (+ out[d] if ADD_SKIP)
template <bool ADD_SKIP>
__global__ __launch_bounds__(256) void aggregate_kern(const float* __restrict__ h,
                                                      const int* __restrict__ row_ptr,
                                                      const int2* __restrict__ epack,
                                                      const float* __restrict__ bias,
                                                      float* __restrict__ out,
                                                      int Nn, int R) {
    const int d = blockIdx.x * 4 + (threadIdx.x >> 6);
    if (d >= Nn) return;
    const int lane = (threadIdx.x & 63) * 4;

    float4 acc = make_float4(0.f, 0.f, 0.f, 0.f);
    for (int r = 0; r < R; ++r) {
        const int key = r * Nn + d;
        int e = row_ptr[key];
        const int end = row_ptr[key + 1];
        const float* hr = h + (size_t)r * Nn * F;
        if (e < end) {
            int2 p = epack[e];
            while (e < end) {
                ++e;
                int2 pn = (e < end) ? epack[e] : p;
                const float v = __int_as_float(p.y);
                const float4 hv = *(const float4*)(hr + (size_t)p.x * F + lane);
                acc.x = fmaf(hv.x, v, acc.x);
                acc.y = fmaf(hv.y, v, acc.y);
                acc.z = fmaf(hv.z, v, acc.z);
                acc.w = fmaf(hv.w, v, acc.w);
                p = pn;
            }
        }
    }
    const float4 bb = *(const float4*)(bias + lane);
    float4 o;
    o.x = fmaxf(acc.x + bb.x, 0.f);
    o.y = fmaxf(acc.y + bb.y, 0.f);
    o.z = fmaxf(acc.z + bb.z, 0.f);
    o.w = fmaxf(acc.w + bb.w, 0.f);
    float* op = out + (size_t)d * F + lane;
    if (ADD_SKIP) {
        const float4 x1 = *(const float4*)op;
        o.x += x1.x; o.y += x1.y; o.z += x1.z; o.w += x1.w;
    }
    *(float4*)op = o;
}

extern "C" void kernel_launch(void* const* d_in, const int* in_sizes, int n_in,
                              void* d_out, int out_size, void* d_ws, size_t ws_size,
                              hipStream_t stream) {
    const float* x    = (const float*)d_in[0];
    const int*   esrc = (const int*)  d_in[1];
    const int*   edst = (const int*)  d_in[2];
    const float* eval = (const float*)d_in[3];
    const float* W1   = (const float*)d_in[4];
    const float* b1   = (const float*)d_in[5];
    const float* W2   = (const float*)d_in[6];
    const float* b2   = (const float*)d_in[7];
    float* out = (float*)d_out;

    const int N = in_sizes[0] / F;
    const int R = in_sizes[4] / (F * F);
    const int E = in_sizes[1] / R;
    const int RE = R * E;
    const int RN = R * N;

    // ---- workspace layout ----
    char* ws = (char*)d_ws;
    float* h4 = (float*)ws;                      // [R, N, F] fp32
    ws += (size_t)R * N * F * sizeof(float);
    int2* epack = (int2*)ws;                     // [R*E] {src, val_bits}
    ws += (size_t)RE * sizeof(int2);
    int* row_ptr = (int*)ws;                     // [R*N + 1] (also used as counts)
    ws += (size_t)(RN + 1) * sizeof(int);
    int* cursor = (int*)ws;                      // [R*N]
    ws += (size_t)RN * sizeof(int);
    int* bsum = (int*)ws;                        // [<=256]

    // ---- build CSR (once; reused by both layers) ----
    hipMemsetAsync(row_ptr, 0, (size_t)(RN + 1) * sizeof(int), stream);
    {
        const int blocks = (RE + 255) / 256;
        count_kern<<<blocks, 256, 0, stream>>>(edst, row_ptr, RE, E, N);
    }
    const int nb_scan = (RN + SCAN_ELEMS - 1) / SCAN_ELEMS;   // 196 for N=50k,R=4
    scan1_kern<<<nb_scan, SCAN_T, 0, stream>>>(row_ptr, bsum, RN);
    scan2_kern<<<1, SCAN_T, 0, stream>>>(bsum, nb_scan);
    scan3_kern<<<(RN + 1 + 255) / 256, 256, 0, stream>>>(row_ptr, bsum, cursor, RN, RE);
    {
        const int blocks = (RE + 255) / 256;
        fill_kern<<<blocks, 256, 0, stream>>>(esrc, edst, eval, cursor, epack, RE, E, N);
    }

    // ---- layer 1: h4[r] = x @ W1[r]; out = relu(agg + b1) ----
    dim3 ggrid((N + BM - 1) / BM, F / BN, R);
    gemm_f32_batched<<<ggrid, 256, 0, stream>>>(x, W1, h4, N);
    aggregate_kern<false><<<(N + 3) / 4, 256, 0, stream>>>(h4, row_ptr, epack, b1, out, N, R);

    // ---- layer 2: h4[r] = out @ W2[r]; out = relu(agg + b2) + out ----
    gemm_f32_batched<<<ggrid, 256, 0, stream>>>(out, W2, h4, N);
    aggregate_kern<true><<<(N + 3) / 4, 256, 0, stream>>>(h4, row_ptr, epack, b2, out, N, R);
}

// Round 3
// 876.981 us; speedup vs baseline: 12.9555x; 1.5268x over previous
//
#include <hip/hip_runtime.h>
#include <hip/hip_bf16.h>

#define F 256
#define SCAN_T 256
#define SCAN_ELEMS 1024

typedef __attribute__((ext_vector_type(8))) short bf16x8;
typedef __attribute__((ext_vector_type(4))) float f32x4;

__device__ __forceinline__ float bf2f(unsigned short u) {
    return __uint_as_float((unsigned)u << 16);
}
__device__ __forceinline__ short f2bf(float x) {
    return (short)__bfloat16_as_ushort(__float2bfloat16(x));
}

// ---------------- convert fp32 [N][256] -> bf16 [Mp][256], zero-pad rows >= N ----------------
__global__ __launch_bounds__(256) void convert_pad(const float* __restrict__ in,
                                                   unsigned short* __restrict__ outb,
                                                   int N, int Mp) {
    int i = blockIdx.x * 256 + threadIdx.x;          // one thread per 8 elements
    int total = Mp * (F / 8);
    if (i >= total) return;
    int row = i >> 5;                                 // 256/8 = 32 groups per row
    int g = (i & 31) * 8;
    bf16x8 v;
    if (row < N) {
        const float* p = in + (size_t)row * F + g;
        float4 a = *(const float4*)p;
        float4 b = *(const float4*)(p + 4);
        v[0] = f2bf(a.x); v[1] = f2bf(a.y); v[2] = f2bf(a.z); v[3] = f2bf(a.w);
        v[4] = f2bf(b.x); v[5] = f2bf(b.y); v[6] = f2bf(b.z); v[7] = f2bf(b.w);
    } else {
        v = (bf16x8){0, 0, 0, 0, 0, 0, 0, 0};
    }
    *(bf16x8*)(outb + (size_t)row * F + g) = v;
}

// ---------------- W [R][256][256] fp32 (k-major) -> WT [R][256][256] bf16 (col-major) ----------------
__global__ __launch_bounds__(256) void transpose_w(const float* __restrict__ W,
                                                   unsigned short* __restrict__ WT) {
    __shared__ float t[32][33];
    int rel = blockIdx.z;
    const float* Wr = W + (size_t)rel * F * F;
    unsigned short* WTr = WT + (size_t)rel * F * F;
    int k0 = blockIdx.x * 32, c0 = blockIdx.y * 32;
    int tx = threadIdx.x & 31, ty = threadIdx.x >> 5;   // ty 0..7
#pragma unroll
    for (int i = 0; i < 32; i += 8)
        t[ty + i][tx] = Wr[(size_t)(k0 + ty + i) * F + c0 + tx];
    __syncthreads();
#pragma unroll
    for (int i = 0; i < 32; i += 8)
        WTr[(size_t)(c0 + ty + i) * F + k0 + tx] = (unsigned short)f2bf(t[tx][ty + i]);
}

// ---------------- MFMA GEMM: H[r] = A @ W[r], bf16 in/out, fp32 accum, no LDS ----------------
// A: bf16 [Mp][256] (rows >= N are zero).  WT: bf16 [R][col][k].  H: bf16 [R][Mp][256].
__global__ __launch_bounds__(256) void gemm_mfma(const unsigned short* __restrict__ A,
                                                 const unsigned short* __restrict__ WT,
                                                 unsigned short* __restrict__ H,
                                                 int Mp, int nrb) {
    // bijective XCD swizzle: nwg = nrb*8 (divisible by 8)
    const int cpx = nrb;                       // nwg/8
    const int L = (blockIdx.x % 8) * cpx + blockIdx.x / 8;
    const int rb  = L >> 3;
    const int sub = L & 7;
    const int rel = sub >> 1;
    const int cb  = sub & 1;

    const int wave = threadIdx.x >> 6;
    const int lane = threadIdx.x & 63;
    const int wr = wave >> 1, wc = wave & 1;

    const int row0 = rb * 128 + wr * 64;
    const int col0 = cb * 128 + wc * 64;

    const unsigned short* Ab = A + (size_t)row0 * F;
    const unsigned short* Bb = WT + ((size_t)rel * F + col0) * F;

    const int lrow = lane & 15;
    const int lk = (lane >> 4) * 8;

    f32x4 acc[4][4] = {};

#pragma unroll 2
    for (int k0 = 0; k0 < F; k0 += 32) {
        bf16x8 a[4], b[4];
#pragma unroll
        for (int m = 0; m < 4; ++m)
            a[m] = *(const bf16x8*)(Ab + (size_t)(m * 16 + lrow) * F + k0 + lk);
#pragma unroll
        for (int n = 0; n < 4; ++n)
            b[n] = *(const bf16x8*)(Bb + (size_t)(n * 16 + lrow) * F + k0 + lk);
#pragma unroll
        for (int m = 0; m < 4; ++m)
#pragma unroll
            for (int n = 0; n < 4; ++n)
                acc[m][n] = __builtin_amdgcn_mfma_f32_16x16x32_bf16(a[m], b[n], acc[m][n], 0, 0, 0);
    }

    // C/D layout: col = lane&15, row = (lane>>4)*4 + q   [m89/m91-verified]
    unsigned short* Hb = H + ((size_t)rel * Mp + row0) * F + col0;
    const int crow = (lane >> 4) * 4;
    const int ccol = lane & 15;
#pragma unroll
    for (int m = 0; m < 4; ++m)
#pragma unroll
        for (int n = 0; n < 4; ++n)
#pragma unroll
            for (int q = 0; q < 4; ++q)
                Hb[(size_t)(m * 16 + crow + q) * F + n * 16 + ccol] =
                    (unsigned short)f2bf(acc[m][n][q]);
}

// ---------------- CSR build ----------------
__global__ __launch_bounds__(256) void count_kern(const int* __restrict__ edst,
                                                  int* __restrict__ counts,
                                                  int total, int E, int Nn) {
    int i = blockIdx.x * blockDim.x + threadIdx.x;
    if (i >= total) return;
    int r = i / E;
    atomicAdd(counts + r * Nn + edst[i], 1);
}

__global__ __launch_bounds__(SCAN_T) void scan1_kern(int* __restrict__ data,
                                                     int* __restrict__ bsum, int n) {
    __shared__ int sh[SCAN_T];
    const int t = threadIdx.x;
    const int base = blockIdx.x * SCAN_ELEMS + t * 4;
    int v[4];
    int tsum = 0;
#pragma unroll
    for (int j = 0; j < 4; ++j) {
        v[j] = (base + j < n) ? data[base + j] : 0;
        tsum += v[j];
    }
    sh[t] = tsum;
    __syncthreads();
    for (int off = 1; off < SCAN_T; off <<= 1) {
        int x = (t >= off) ? sh[t - off] : 0;
        __syncthreads();
        sh[t] += x;
        __syncthreads();
    }
    if (t == SCAN_T - 1) bsum[blockIdx.x] = sh[t];
    int run = sh[t] - tsum;
#pragma unroll
    for (int j = 0; j < 4; ++j) {
        if (base + j < n) data[base + j] = run;
        run += v[j];
    }
}

__global__ __launch_bounds__(SCAN_T) void scan2_kern(int* __restrict__ bsum, int nb) {
    __shared__ int sh[SCAN_T];
    const int t = threadIdx.x;
    int val = (t < nb) ? bsum[t] : 0;
    sh[t] = val;
    __syncthreads();
    for (int off = 1; off < SCAN_T; off <<= 1) {
        int x = (t >= off) ? sh[t - off] : 0;
        __syncthreads();
        sh[t] += x;
        __syncthreads();
    }
    if (t < nb) bsum[t] = sh[t] - val;
}

__global__ __launch_bounds__(256) void scan3_kern(int* __restrict__ row_ptr,
                                                  const int* __restrict__ bsum,
                                                  int* __restrict__ cursor,
                                                  int n, int total) {
    int i = blockIdx.x * blockDim.x + threadIdx.x;
    if (i < n) {
        int v = row_ptr[i] + bsum[i >> 10];
        row_ptr[i] = v;
        cursor[i] = v;
    } else if (i == n) {
        row_ptr[n] = total;
    }
}

__global__ __launch_bounds__(256) void fill_kern(const int* __restrict__ esrc,
                                                 const int* __restrict__ edst,
                                                 const float* __restrict__ eval,
                                                 int* __restrict__ cursor,
                                                 int2* __restrict__ epack,
                                                 int total, int E, int Nn) {
    int i = blockIdx.x * blockDim.x + threadIdx.x;
    if (i >= total) return;
    int r = i / E;
    int key = r * Nn + edst[i];
    int pos = atomicAdd(cursor + key, 1);
    epack[pos] = make_int2(esrc[i], __float_as_int(eval[i]));
}

// ---------------- Aggregate (bf16 h): one wave per dst row ----------------
template <bool ADD_SKIP>
__global__ __launch_bounds__(256) void aggregate_bf16(const unsigned short* __restrict__ h,
                                                      const int* __restrict__ row_ptr,
                                                      const int2* __restrict__ epack,
                                                      const float* __restrict__ bias,
                                                      float* __restrict__ out,
                                                      int Nn, int Mp, int R) {
    const int d = blockIdx.x * 4 + (threadIdx.x >> 6);
    if (d >= Nn) return;
    const int lane4 = (threadIdx.x & 63) * 4;     // feature offset (4 bf16 / lane)

    float4 acc = make_float4(0.f, 0.f, 0.f, 0.f);
    for (int r = 0; r < R; ++r) {
        const int key = r * Nn + d;
        int e = row_ptr[key];
        const int end = row_ptr[key + 1];
        const unsigned short* hr = h + (size_t)r * Mp * F;
        if (e < end) {
            int2 p = epack[e];
            while (e < end) {
                ++e;
                int2 pn = (e < end) ? epack[e] : p;
                const float v = __int_as_float(p.y);
                ushort4 hv = *(const ushort4*)(hr + (size_t)p.x * F + lane4);
                acc.x = fmaf(bf2f(hv.x), v, acc.x);
                acc.y = fmaf(bf2f(hv.y), v, acc.y);
                acc.z = fmaf(bf2f(hv.z), v, acc.z);
                acc.w = fmaf(bf2f(hv.w), v, acc.w);
                p = pn;
            }
        }
    }
    const float4 bb = *(const float4*)(bias + lane4);
    float4 o;
    o.x = fmaxf(acc.x + bb.x, 0.f);
    o.y = fmaxf(acc.y + bb.y, 0.f);
    o.z = fmaxf(acc.z + bb.z, 0.f);
    o.w = fmaxf(acc.w + bb.w, 0.f);
    float* op = out + (size_t)d * F + lane4;
    if (ADD_SKIP) {
        const float4 x1 = *(const float4*)op;
        o.x += x1.x; o.y += x1.y; o.z += x1.z; o.w += x1.w;
    }
    *(float4*)op = o;
}

extern "C" void kernel_launch(void* const* d_in, const int* in_sizes, int n_in,
                              void* d_out, int out_size, void* d_ws, size_t ws_size,
                              hipStream_t stream) {
    const float* x    = (const float*)d_in[0];
    const int*   esrc = (const int*)  d_in[1];
    const int*   edst = (const int*)  d_in[2];
    const float* eval = (const float*)d_in[3];
    const float* W1   = (const float*)d_in[4];
    const float* b1   = (const float*)d_in[5];
    const float* W2   = (const float*)d_in[6];
    const float* b2   = (const float*)d_in[7];
    float* out = (float*)d_out;

    const int N = in_sizes[0] / F;
    const int R = in_sizes[4] / (F * F);
    const int E = in_sizes[1] / R;
    const int RE = R * E;
    const int RN = R * N;
    const int nrb = (N + 127) / 128;
    const int Mp = nrb * 128;

    // ---- workspace layout ----
    char* ws = (char*)d_ws;
    unsigned short* h4 = (unsigned short*)ws;            // [R][Mp][256] bf16
    ws += (size_t)R * Mp * F * sizeof(unsigned short);
    unsigned short* Abf = (unsigned short*)ws;           // [Mp][256] bf16
    ws += (size_t)Mp * F * sizeof(unsigned short);
    unsigned short* WT1 = (unsigned short*)ws;           // [R][256][256] bf16 (col-major)
    ws += (size_t)R * F * F * sizeof(unsigned short);
    unsigned short* WT2 = (unsigned short*)ws;
    ws += (size_t)R * F * F * sizeof(unsigned short);
    int2* epack = (int2*)ws;                             // [R*E]
    ws += (size_t)RE * sizeof(int2);
    int* row_ptr = (int*)ws;                             // [R*N + 1]
    ws += (size_t)(RN + 1) * sizeof(int);
    int* cursor = (int*)ws;                              // [R*N]
    ws += (size_t)RN * sizeof(int);
    int* bsum = (int*)ws;                                // [<=256]

    // ---- CSR build (reused by both layers) ----
    hipMemsetAsync(row_ptr, 0, (size_t)(RN + 1) * sizeof(int), stream);
    count_kern<<<(RE + 255) / 256, 256, 0, stream>>>(edst, row_ptr, RE, E, N);
    const int nb_scan = (RN + SCAN_ELEMS - 1) / SCAN_ELEMS;
    scan1_kern<<<nb_scan, SCAN_T, 0, stream>>>(row_ptr, bsum, RN);
    scan2_kern<<<1, SCAN_T, 0, stream>>>(bsum, nb_scan);
    scan3_kern<<<(RN + 1 + 255) / 256, 256, 0, stream>>>(row_ptr, bsum, cursor, RN, RE);
    fill_kern<<<(RE + 255) / 256, 256, 0, stream>>>(esrc, edst, eval, cursor, epack, RE, E, N);

    // ---- weight transpose+convert (once) ----
    dim3 tgrid(F / 32, F / 32, R);
    transpose_w<<<tgrid, 256, 0, stream>>>(W1, WT1);
    transpose_w<<<tgrid, 256, 0, stream>>>(W2, WT2);

    const int cvt_blocks = (Mp * (F / 8) + 255) / 256;
    const int ggrid = nrb * 8;

    // ---- layer 1 ----
    convert_pad<<<cvt_blocks, 256, 0, stream>>>(x, Abf, N, Mp);
    gemm_mfma<<<ggrid, 256, 0, stream>>>(Abf, WT1, h4, Mp, nrb);
    aggregate_bf16<false><<<(N + 3) / 4, 256, 0, stream>>>(h4, row_ptr, epack, b1, out, N, Mp, R);

    // ---- layer 2 ----
    convert_pad<<<cvt_blocks, 256, 0, stream>>>(out, Abf, N, Mp);
    gemm_mfma<<<ggrid, 256, 0, stream>>>(Abf, WT2, h4, Mp, nrb);
    aggregate_bf16<true><<<(N + 3) / 4, 256, 0, stream>>>(h4, row_ptr, epack, b2, out, N, Mp, R);
}

// Round 4
// 699.406 us; speedup vs baseline: 16.2449x; 1.2539x over previous
//
#include <hip/hip_runtime.h>
#include <hip/hip_bf16.h>

#define F 256
#define KC 1024           // concatenated K = R * F
#define SCAN_T 256
#define SCAN_ELEMS 1024

typedef __attribute__((ext_vector_type(8))) short bf16x8;
typedef __attribute__((ext_vector_type(4))) float f32x4;

__device__ __forceinline__ float bf2f(unsigned short u) {
    return __uint_as_float((unsigned)u << 16);
}
__device__ __forceinline__ unsigned short f2bf(float x) {
    return __bfloat16_as_ushort(__float2bfloat16(x));
}

// ---------------- convert fp32 [N][256] -> bf16 [N][256] ----------------
__global__ __launch_bounds__(256) void convert_bf16(const float* __restrict__ in,
                                                    unsigned short* __restrict__ outb,
                                                    int total8) {
    int i = blockIdx.x * 256 + threadIdx.x;          // one thread per 8 elements
    if (i >= total8) return;
    const float* p = in + (size_t)i * 8;
    float4 a = *(const float4*)p;
    float4 b = *(const float4*)(p + 4);
    bf16x8 v;
    v[0] = f2bf(a.x); v[1] = f2bf(a.y); v[2] = f2bf(a.z); v[3] = f2bf(a.w);
    v[4] = f2bf(b.x); v[5] = f2bf(b.y); v[6] = f2bf(b.z); v[7] = f2bf(b.w);
    *(bf16x8*)(outb + (size_t)i * 8) = v;
}

// ---- W [R][256(k)][256(c)] fp32 -> WT [256(c)][1024(r*256+k)] bf16 ----
__global__ __launch_bounds__(256) void transpose_wcat(const float* __restrict__ W,
                                                      unsigned short* __restrict__ WT) {
    __shared__ float t[32][33];
    const int rel = blockIdx.z;
    const float* Wr = W + (size_t)rel * F * F;
    const int k0 = blockIdx.x * 32, c0 = blockIdx.y * 32;
    const int tx = threadIdx.x & 31, ty = threadIdx.x >> 5;   // ty 0..7
#pragma unroll
    for (int i = 0; i < 32; i += 8)
        t[ty + i][tx] = Wr[(size_t)(k0 + ty + i) * F + c0 + tx];   // t[k][c]
    __syncthreads();
#pragma unroll
    for (int i = 0; i < 32; i += 8)
        WT[(size_t)(c0 + ty + i) * KC + rel * F + k0 + tx] = f2bf(t[tx][ty + i]);
}

// ---------------- CSR build ----------------
__global__ __launch_bounds__(256) void count_kern(const int* __restrict__ edst,
                                                  int* __restrict__ counts,
                                                  int total, int E, int Nn) {
    int i = blockIdx.x * blockDim.x + threadIdx.x;
    if (i >= total) return;
    int r = i / E;
    atomicAdd(counts + r * Nn + edst[i], 1);
}

__global__ __launch_bounds__(SCAN_T) void scan1_kern(int* __restrict__ data,
                                                     int* __restrict__ bsum, int n) {
    __shared__ int sh[SCAN_T];
    const int t = threadIdx.x;
    const int base = blockIdx.x * SCAN_ELEMS + t * 4;
    int v[4];
    int tsum = 0;
#pragma unroll
    for (int j = 0; j < 4; ++j) {
        v[j] = (base + j < n) ? data[base + j] : 0;
        tsum += v[j];
    }
    sh[t] = tsum;
    __syncthreads();
    for (int off = 1; off < SCAN_T; off <<= 1) {
        int x = (t >= off) ? sh[t - off] : 0;
        __syncthreads();
        sh[t] += x;
        __syncthreads();
    }
    if (t == SCAN_T - 1) bsum[blockIdx.x] = sh[t];
    int run = sh[t] - tsum;
#pragma unroll
    for (int j = 0; j < 4; ++j) {
        if (base + j < n) data[base + j] = run;
        run += v[j];
    }
}

__global__ __launch_bounds__(SCAN_T) void scan2_kern(int* __restrict__ bsum, int nb) {
    __shared__ int sh[SCAN_T];
    const int t = threadIdx.x;
    int val = (t < nb) ? bsum[t] : 0;
    sh[t] = val;
    __syncthreads();
    for (int off = 1; off < SCAN_T; off <<= 1) {
        int x = (t >= off) ? sh[t - off] : 0;
        __syncthreads();
        sh[t] += x;
        __syncthreads();
    }
    if (t < nb) bsum[t] = sh[t] - val;
}

__global__ __launch_bounds__(256) void scan3_kern(int* __restrict__ row_ptr,
                                                  const int* __restrict__ bsum,
                                                  int* __restrict__ cursor,
                                                  int n, int total) {
    int i = blockIdx.x * blockDim.x + threadIdx.x;
    if (i < n) {
        int v = row_ptr[i] + bsum[i >> 10];
        row_ptr[i] = v;
        cursor[i] = v;
    } else if (i == n) {
        row_ptr[n] = total;
    }
}

__global__ __launch_bounds__(256) void fill_kern(const int* __restrict__ esrc,
                                                 const int* __restrict__ edst,
                                                 const float* __restrict__ eval,
                                                 int* __restrict__ cursor,
                                                 int2* __restrict__ epack,
                                                 int total, int E, int Nn) {
    int i = blockIdx.x * blockDim.x + threadIdx.x;
    if (i >= total) return;
    int r = i / E;
    int key = r * Nn + edst[i];
    int pos = atomicAdd(cursor + key, 1);
    epack[pos] = make_int2(esrc[i], __float_as_int(eval[i]));
}

// ---------------- Gather-aggregate on input features ----------------
// Y[d][r*256 + f] = sum_{e in CSR(r,d)} val_e * xb[src_e][f]
// one wave per (d, r); 4 waves per block share d.
__global__ __launch_bounds__(256) void aggregate_g(const unsigned short* __restrict__ xb,
                                                   const int* __restrict__ row_ptr,
                                                   const int2* __restrict__ epack,
                                                   unsigned short* __restrict__ Y,
                                                   int Nn) {
    const int d = blockIdx.x;
    const int r = threadIdx.x >> 6;
    if (d >= Nn) return;
    const int lane4 = (threadIdx.x & 63) * 4;

    const int key = r * Nn + d;
    int e = row_ptr[key];
    const int end = row_ptr[key + 1];

    float4 acc = make_float4(0.f, 0.f, 0.f, 0.f);
    // 4-wide unroll: 4 independent gathers in flight per wave
    for (; e + 4 <= end; e += 4) {
        int2 p0 = epack[e + 0];
        int2 p1 = epack[e + 1];
        int2 p2 = epack[e + 2];
        int2 p3 = epack[e + 3];
        ushort4 h0 = *(const ushort4*)(xb + (size_t)p0.x * F + lane4);
        ushort4 h1 = *(const ushort4*)(xb + (size_t)p1.x * F + lane4);
        ushort4 h2 = *(const ushort4*)(xb + (size_t)p2.x * F + lane4);
        ushort4 h3 = *(const ushort4*)(xb + (size_t)p3.x * F + lane4);
        const float v0 = __int_as_float(p0.y), v1 = __int_as_float(p1.y);
        const float v2 = __int_as_float(p2.y), v3 = __int_as_float(p3.y);
        acc.x = fmaf(bf2f(h0.x), v0, acc.x); acc.y = fmaf(bf2f(h0.y), v0, acc.y);
        acc.z = fmaf(bf2f(h0.z), v0, acc.z); acc.w = fmaf(bf2f(h0.w), v0, acc.w);
        acc.x = fmaf(bf2f(h1.x), v1, acc.x); acc.y = fmaf(bf2f(h1.y), v1, acc.y);
        acc.z = fmaf(bf2f(h1.z), v1, acc.z); acc.w = fmaf(bf2f(h1.w), v1, acc.w);
        acc.x = fmaf(bf2f(h2.x), v2, acc.x); acc.y = fmaf(bf2f(h2.y), v2, acc.y);
        acc.z = fmaf(bf2f(h2.z), v2, acc.z); acc.w = fmaf(bf2f(h2.w), v2, acc.w);
        acc.x = fmaf(bf2f(h3.x), v3, acc.x); acc.y = fmaf(bf2f(h3.y), v3, acc.y);
        acc.z = fmaf(bf2f(h3.z), v3, acc.z); acc.w = fmaf(bf2f(h3.w), v3, acc.w);
    }
    for (; e < end; ++e) {
        int2 p = epack[e];
        const float v = __int_as_float(p.y);
        ushort4 hv = *(const ushort4*)(xb + (size_t)p.x * F + lane4);
        acc.x = fmaf(bf2f(hv.x), v, acc.x);
        acc.y = fmaf(bf2f(hv.y), v, acc.y);
        acc.z = fmaf(bf2f(hv.z), v, acc.z);
        acc.w = fmaf(bf2f(hv.w), v, acc.w);
    }
    ushort4 o;
    o.x = f2bf(acc.x); o.y = f2bf(acc.y); o.z = f2bf(acc.z); o.w = f2bf(acc.w);
    *(ushort4*)(Y + (size_t)d * KC + r * F + lane4) = o;
}

// ---------------- Fused MFMA GEMM + epilogue ----------------
// C = Y[Mp,1024] @ WT^T  (WT: [256 cols][1024 k] bf16)
// LAYER1: x1 = relu(C + b); d_out = x1 (fp32); x1b = bf16(x1)
// LAYER2: d_out = relu(C + b) + d_out
template <bool LAYER2>
__global__ __launch_bounds__(512) void gemm_fused(const unsigned short* __restrict__ A,
                                                  const unsigned short* __restrict__ WT,
                                                  const float* __restrict__ bias,
                                                  float* __restrict__ out,
                                                  unsigned short* __restrict__ x1b,
                                                  int Nn, int nrb) {
    // bijective XCD swizzle over nrb blocks (m204)
    const int xcd = blockIdx.x & 7;
    const int j = blockIdx.x >> 3;
    const int q = nrb >> 3, rr = nrb & 7;
    const int rb = (xcd < rr ? xcd * (q + 1) : rr * (q + 1) + (xcd - rr) * q) + j;

    const int wave = threadIdx.x >> 6;
    const int lane = threadIdx.x & 63;
    const int wr = wave >> 2, wc = wave & 3;

    const int row0 = rb * 128 + wr * 64;
    const int col0 = wc * 64;

    const unsigned short* Ab = A + (size_t)row0 * KC;
    const unsigned short* Bb = WT + (size_t)col0 * KC;

    const int lrow = lane & 15;
    const int lk = (lane >> 4) * 8;

    f32x4 acc[4][4] = {};

#pragma unroll 2
    for (int k0 = 0; k0 < KC; k0 += 32) {
        bf16x8 a[4], b[4];
#pragma unroll
        for (int m = 0; m < 4; ++m)
            a[m] = *(const bf16x8*)(Ab + (size_t)(m * 16 + lrow) * KC + k0 + lk);
#pragma unroll
        for (int n = 0; n < 4; ++n)
            b[n] = *(const bf16x8*)(Bb + (size_t)(n * 16 + lrow) * KC + k0 + lk);
#pragma unroll
        for (int m = 0; m < 4; ++m)
#pragma unroll
            for (int n = 0; n < 4; ++n)
                acc[m][n] = __builtin_amdgcn_mfma_f32_16x16x32_bf16(a[m], b[n], acc[m][n], 0, 0, 0);
    }

    // C/D layout: col = lane&15, row = (lane>>4)*4 + q
    const int crow = (lane >> 4) * 4;
    const int ccol = lane & 15;
#pragma unroll
    for (int m = 0; m < 4; ++m) {
#pragma unroll
        for (int q4 = 0; q4 < 4; ++q4) {
            const int grow = row0 + m * 16 + crow + q4;
            if (grow >= Nn) continue;
#pragma unroll
            for (int n = 0; n < 4; ++n) {
                const int gcol = col0 + n * 16 + ccol;
                float v = acc[m][n][q4] + bias[gcol];
                v = fmaxf(v, 0.f);
                const size_t oi = (size_t)grow * F + gcol;
                if (LAYER2) {
                    out[oi] = v + out[oi];
                } else {
                    out[oi] = v;
                    x1b[oi] = f2bf(v);
                }
            }
        }
    }
}

extern "C" void kernel_launch(void* const* d_in, const int* in_sizes, int n_in,
                              void* d_out, int out_size, void* d_ws, size_t ws_size,
                              hipStream_t stream) {
    const float* x    = (const float*)d_in[0];
    const int*   esrc = (const int*)  d_in[1];
    const int*   edst = (const int*)  d_in[2];
    const float* eval = (const float*)d_in[3];
    const float* W1   = (const float*)d_in[4];
    const float* b1   = (const float*)d_in[5];
    const float* W2   = (const float*)d_in[6];
    const float* b2   = (const float*)d_in[7];
    float* out = (float*)d_out;

    const int N = in_sizes[0] / F;
    const int R = in_sizes[4] / (F * F);
    const int E = in_sizes[1] / R;
    const int RE = R * E;
    const int RN = R * N;
    const int nrb = (N + 127) / 128;
    const int Mp = nrb * 128;

    // ---- workspace layout ----
    char* ws = (char*)d_ws;
    unsigned short* Y = (unsigned short*)ws;             // [Mp][1024] bf16
    ws += (size_t)Mp * KC * sizeof(unsigned short);
    unsigned short* xb = (unsigned short*)ws;            // [N][256] bf16
    ws += (size_t)N * F * sizeof(unsigned short);
    unsigned short* x1b = (unsigned short*)ws;           // [N][256] bf16
    ws += (size_t)N * F * sizeof(unsigned short);
    unsigned short* WTc1 = (unsigned short*)ws;          // [256][1024] bf16
    ws += (size_t)F * KC * sizeof(unsigned short);
    unsigned short* WTc2 = (unsigned short*)ws;
    ws += (size_t)F * KC * sizeof(unsigned short);
    int2* epack = (int2*)ws;                             // [R*E]
    ws += (size_t)RE * sizeof(int2);
    int* row_ptr = (int*)ws;                             // [R*N + 1]
    ws += (size_t)(RN + 1) * sizeof(int);
    int* cursor = (int*)ws;                              // [R*N]
    ws += (size_t)RN * sizeof(int);
    int* bsum = (int*)ws;

    // ---- CSR build (reused by both layers) ----
    hipMemsetAsync(row_ptr, 0, (size_t)(RN + 1) * sizeof(int), stream);
    count_kern<<<(RE + 255) / 256, 256, 0, stream>>>(edst, row_ptr, RE, E, N);
    const int nb_scan = (RN + SCAN_ELEMS - 1) / SCAN_ELEMS;
    scan1_kern<<<nb_scan, SCAN_T, 0, stream>>>(row_ptr, bsum, RN);
    scan2_kern<<<1, SCAN_T, 0, stream>>>(bsum, nb_scan);
    scan3_kern<<<(RN + 1 + 255) / 256, 256, 0, stream>>>(row_ptr, bsum, cursor, RN, RE);
    fill_kern<<<(RE + 255) / 256, 256, 0, stream>>>(esrc, edst, eval, cursor, epack, RE, E, N);

    // ---- weight transpose+convert (once) ----
    dim3 tgrid(F / 32, F / 32, R);
    transpose_wcat<<<tgrid, 256, 0, stream>>>(W1, WTc1);
    transpose_wcat<<<tgrid, 256, 0, stream>>>(W2, WTc2);

    // ---- input conversion (once) ----
    convert_bf16<<<(N * (F / 8) + 255) / 256, 256, 0, stream>>>(x, xb, N * (F / 8));

    const int ggrid = nrb * 8 - 7;   // swizzle maps [0, nrb*8) -> need exactly nrb*8? use full
    // layer 1: Y = gather(xb); out/x1b = relu(Y @ Wc1 + b1)
    aggregate_g<<<N, 256, 0, stream>>>(xb, row_ptr, epack, Y, N);
    gemm_fused<false><<<nrb * 8 / 8 * 8 >= nrb ? nrb : nrb, 512, 0, stream>>>(Y, WTc1, b1, out, x1b, N, nrb);

    // layer 2: Y = gather(x1b); out = relu(Y @ Wc2 + b2) + out
    aggregate_g<<<N, 256, 0, stream>>>(x1b, row_ptr, epack, Y, N);
    gemm_fused<true><<<nrb, 512, 0, stream>>>(Y, WTc2, b2, out, x1b, N, nrb);
}

// Round 5
// 569.496 us; speedup vs baseline: 19.9506x; 1.2281x over previous
//
#include <hip/hip_runtime.h>
#include <hip/hip_bf16.h>

#define F 256
#define KC 1024           // concatenated K = R * F
#define BM 128
#define BN 128
#define BK 32
#define SCAN_T 256
#define SCAN_ELEMS 1024

typedef __attribute__((ext_vector_type(8))) short bf16x8;
typedef __attribute__((ext_vector_type(4))) float f32x4;
typedef __attribute__((address_space(3))) unsigned int* lds_u32p;
typedef const __attribute__((address_space(1))) unsigned int* glb_u32p;

__device__ __forceinline__ float bf2f(unsigned short u) {
    return __uint_as_float((unsigned)u << 16);
}
__device__ __forceinline__ unsigned short f2bf(float x) {
    return __bfloat16_as_ushort(__float2bfloat16(x));
}

// ---------------- convert fp32 [N][256] -> bf16 [N][256] ----------------
__global__ __launch_bounds__(256) void convert_bf16(const float* __restrict__ in,
                                                    unsigned short* __restrict__ outb,
                                                    int total8) {
    int i = blockIdx.x * 256 + threadIdx.x;
    if (i >= total8) return;
    const float* p = in + (size_t)i * 8;
    float4 a = *(const float4*)p;
    float4 b = *(const float4*)(p + 4);
    bf16x8 v;
    v[0] = f2bf(a.x); v[1] = f2bf(a.y); v[2] = f2bf(a.z); v[3] = f2bf(a.w);
    v[4] = f2bf(b.x); v[5] = f2bf(b.y); v[6] = f2bf(b.z); v[7] = f2bf(b.w);
    *(bf16x8*)(outb + (size_t)i * 8) = v;
}

// ---- W [R][256(k)][256(c)] fp32 -> WT [256(c)][1024(r*256+k)] bf16 ----
__global__ __launch_bounds__(256) void transpose_wcat(const float* __restrict__ W,
                                                      unsigned short* __restrict__ WT) {
    __shared__ float t[32][33];
    const int rel = blockIdx.z;
    const float* Wr = W + (size_t)rel * F * F;
    const int k0 = blockIdx.x * 32, c0 = blockIdx.y * 32;
    const int tx = threadIdx.x & 31, ty = threadIdx.x >> 5;
#pragma unroll
    for (int i = 0; i < 32; i += 8)
        t[ty + i][tx] = Wr[(size_t)(k0 + ty + i) * F + c0 + tx];
    __syncthreads();
#pragma unroll
    for (int i = 0; i < 32; i += 8)
        WT[(size_t)(c0 + ty + i) * KC + rel * F + k0 + tx] = f2bf(t[tx][ty + i]);
}

// ---------------- CSR build ----------------
__global__ __launch_bounds__(256) void count_kern(const int* __restrict__ edst,
                                                  int* __restrict__ counts,
                                                  int total, int E, int Nn) {
    int i = blockIdx.x * blockDim.x + threadIdx.x;
    if (i >= total) return;
    int r = i / E;
    atomicAdd(counts + r * Nn + edst[i], 1);
}

__global__ __launch_bounds__(SCAN_T) void scan1_kern(int* __restrict__ data,
                                                     int* __restrict__ bsum, int n) {
    __shared__ int sh[SCAN_T];
    const int t = threadIdx.x;
    const int base = blockIdx.x * SCAN_ELEMS + t * 4;
    int v[4];
    int tsum = 0;
#pragma unroll
    for (int j = 0; j < 4; ++j) {
        v[j] = (base + j < n) ? data[base + j] : 0;
        tsum += v[j];
    }
    sh[t] = tsum;
    __syncthreads();
    for (int off = 1; off < SCAN_T; off <<= 1) {
        int x = (t >= off) ? sh[t - off] : 0;
        __syncthreads();
        sh[t] += x;
        __syncthreads();
    }
    if (t == SCAN_T - 1) bsum[blockIdx.x] = sh[t];
    int run = sh[t] - tsum;
#pragma unroll
    for (int j = 0; j < 4; ++j) {
        if (base + j < n) data[base + j] = run;
        run += v[j];
    }
}

__global__ __launch_bounds__(SCAN_T) void scan2_kern(int* __restrict__ bsum, int nb) {
    __shared__ int sh[SCAN_T];
    const int t = threadIdx.x;
    int val = (t < nb) ? bsum[t] : 0;
    sh[t] = val;
    __syncthreads();
    for (int off = 1; off < SCAN_T; off <<= 1) {
        int x = (t >= off) ? sh[t - off] : 0;
        __syncthreads();
        sh[t] += x;
        __syncthreads();
    }
    if (t < nb) bsum[t] = sh[t] - val;
}

__global__ __launch_bounds__(256) void scan3_kern(int* __restrict__ row_ptr,
                                                  const int* __restrict__ bsum,
                                                  int* __restrict__ cursor,
                                                  int n, int total) {
    int i = blockIdx.x * blockDim.x + threadIdx.x;
    if (i < n) {
        int v = row_ptr[i] + bsum[i >> 10];
        row_ptr[i] = v;
        cursor[i] = v;
    } else if (i == n) {
        row_ptr[n] = total;
    }
}

__global__ __launch_bounds__(256) void fill_kern(const int* __restrict__ esrc,
                                                 const int* __restrict__ edst,
                                                 const float* __restrict__ eval,
                                                 int* __restrict__ cursor,
                                                 int2* __restrict__ epack,
                                                 int total, int E, int Nn) {
    int i = blockIdx.x * blockDim.x + threadIdx.x;
    if (i >= total) return;
    int r = i / E;
    int key = r * Nn + edst[i];
    int pos = atomicAdd(cursor + key, 1);
    epack[pos] = make_int2(esrc[i], __float_as_int(eval[i]));
}

// ---------------- Gather-aggregate on input features ----------------
// Y[d][r*256 + f] = sum_{e in CSR(r,d)} val_e * xb[src_e][f]; one wave per (d,r)
__global__ __launch_bounds__(256) void aggregate_g(const unsigned short* __restrict__ xb,
                                                   const int* __restrict__ row_ptr,
                                                   const int2* __restrict__ epack,
                                                   unsigned short* __restrict__ Y,
                                                   int Nn) {
    const int d = blockIdx.x;
    const int r = threadIdx.x >> 6;
    if (d >= Nn) return;
    const int lane4 = (threadIdx.x & 63) * 4;

    const int key = r * Nn + d;
    int e = row_ptr[key];
    const int end = row_ptr[key + 1];

    float4 acc = make_float4(0.f, 0.f, 0.f, 0.f);
    for (; e + 4 <= end; e += 4) {
        int2 p0 = epack[e + 0];
        int2 p1 = epack[e + 1];
        int2 p2 = epack[e + 2];
        int2 p3 = epack[e + 3];
        ushort4 h0 = *(const ushort4*)(xb + (size_t)p0.x * F + lane4);
        ushort4 h1 = *(const ushort4*)(xb + (size_t)p1.x * F + lane4);
        ushort4 h2 = *(const ushort4*)(xb + (size_t)p2.x * F + lane4);
        ushort4 h3 = *(const ushort4*)(xb + (size_t)p3.x * F + lane4);
        const float v0 = __int_as_float(p0.y), v1 = __int_as_float(p1.y);
        const float v2 = __int_as_float(p2.y), v3 = __int_as_float(p3.y);
        acc.x = fmaf(bf2f(h0.x), v0, acc.x); acc.y = fmaf(bf2f(h0.y), v0, acc.y);
        acc.z = fmaf(bf2f(h0.z), v0, acc.z); acc.w = fmaf(bf2f(h0.w), v0, acc.w);
        acc.x = fmaf(bf2f(h1.x), v1, acc.x); acc.y = fmaf(bf2f(h1.y), v1, acc.y);
        acc.z = fmaf(bf2f(h1.z), v1, acc.z); acc.w = fmaf(bf2f(h1.w), v1, acc.w);
        acc.x = fmaf(bf2f(h2.x), v2, acc.x); acc.y = fmaf(bf2f(h2.y), v2, acc.y);
        acc.z = fmaf(bf2f(h2.z), v2, acc.z); acc.w = fmaf(bf2f(h2.w), v2, acc.w);
        acc.x = fmaf(bf2f(h3.x), v3, acc.x); acc.y = fmaf(bf2f(h3.y), v3, acc.y);
        acc.z = fmaf(bf2f(h3.z), v3, acc.z); acc.w = fmaf(bf2f(h3.w), v3, acc.w);
    }
    for (; e < end; ++e) {
        int2 p = epack[e];
        const float v = __int_as_float(p.y);
        ushort4 hv = *(const ushort4*)(xb + (size_t)p.x * F + lane4);
        acc.x = fmaf(bf2f(hv.x), v, acc.x);
        acc.y = fmaf(bf2f(hv.y), v, acc.y);
        acc.z = fmaf(bf2f(hv.z), v, acc.z);
        acc.w = fmaf(bf2f(hv.w), v, acc.w);
    }
    ushort4 o;
    o.x = f2bf(acc.x); o.y = f2bf(acc.y); o.z = f2bf(acc.z); o.w = f2bf(acc.w);
    *(ushort4*)(Y + (size_t)d * KC + r * F + lane4) = o;
}

// ---------------- LDS-staged MFMA GEMM + fused epilogue (m97 structure) --------
// C = Y[Mp,1024] @ WT^T  (WT: [256 cols][1024 k] bf16)
// LAYER1: out = relu(C+b) fp32; x1b = bf16(same)
// LAYER2: out = relu(C+b) + out
template <bool LAYER2>
__global__ __launch_bounds__(256) void gemm_fused(const unsigned short* __restrict__ A,
                                                  const unsigned short* __restrict__ WT,
                                                  const float* __restrict__ bias,
                                                  float* __restrict__ out,
                                                  unsigned short* __restrict__ x1b,
                                                  int Nn, int nwg) {
    __shared__ unsigned short As[BM][BK];   // 8 KB, linear row-major (64 B rows)
    __shared__ unsigned short Bs[BN][BK];   // 8 KB

    // bijective XCD swizzle (m204): consecutive swz share an A row-panel per XCD
    const int xcd = blockIdx.x % 8;
    const int j = blockIdx.x / 8;
    const int q = nwg / 8, rr = nwg % 8;
    const int swz = (xcd < rr ? xcd * (q + 1) : rr * (q + 1) + (xcd - rr) * q) + j;
    const int rb = swz >> 1;
    const int cb = swz & 1;

    const int tid = threadIdx.x;
    const int wave = tid >> 6, lane = tid & 63;
    const int wr = wave >> 1, wc = wave & 1;
    const int row0 = rb * BM;
    const int col0 = cb * BN;

    const int lrow = lane & 15, lk8 = (lane >> 4) * 8;

    // staging: each global_load_lds call moves 256 thr x 16 B = 64 rows x 64 B
    const int srow = wave * 16 + (lane >> 2);   // + i*64
    const int scol = (lane & 3) * 8;            // element offset in k

    f32x4 acc[4][4] = {};

    for (int k0 = 0; k0 < KC; k0 += BK) {
#pragma unroll
        for (int i = 0; i < 2; ++i) {
            const unsigned short* gA = A + (size_t)(row0 + i * 64 + srow) * KC + k0 + scol;
            __builtin_amdgcn_global_load_lds((glb_u32p)gA,
                (lds_u32p)&As[i * 64 + wave * 16][0], 16, 0, 0);
        }
#pragma unroll
        for (int i = 0; i < 2; ++i) {
            const unsigned short* gB = WT + (size_t)(col0 + i * 64 + srow) * KC + k0 + scol;
            __builtin_amdgcn_global_load_lds((glb_u32p)gB,
                (lds_u32p)&Bs[i * 64 + wave * 16][0], 16, 0, 0);
        }
        __syncthreads();

        bf16x8 a[4], b[4];
#pragma unroll
        for (int m = 0; m < 4; ++m)
            a[m] = *(const bf16x8*)&As[wr * 64 + m * 16 + lrow][lk8];
#pragma unroll
        for (int n = 0; n < 4; ++n)
            b[n] = *(const bf16x8*)&Bs[wc * 64 + n * 16 + lrow][lk8];
#pragma unroll
        for (int m = 0; m < 4; ++m)
#pragma unroll
            for (int n = 0; n < 4; ++n)
                acc[m][n] = __builtin_amdgcn_mfma_f32_16x16x32_bf16(a[m], b[n], acc[m][n], 0, 0, 0);
        __syncthreads();
    }

    // C/D layout: col = lane&15, row = (lane>>4)*4 + q  [m89/m91]
    const int crow = (lane >> 4) * 4;
    const int ccol = lane & 15;
#pragma unroll
    for (int m = 0; m < 4; ++m) {
#pragma unroll
        for (int q4 = 0; q4 < 4; ++q4) {
            const int grow = row0 + wr * 64 + m * 16 + crow + q4;
            if (grow >= Nn) continue;
#pragma unroll
            for (int n = 0; n < 4; ++n) {
                const int gcol = col0 + wc * 64 + n * 16 + ccol;
                float v = acc[m][n][q4] + bias[gcol];
                v = fmaxf(v, 0.f);
                const size_t oi = (size_t)grow * F + gcol;
                if (LAYER2) {
                    out[oi] = v + out[oi];
                } else {
                    out[oi] = v;
                    x1b[oi] = f2bf(v);
                }
            }
        }
    }
}

extern "C" void kernel_launch(void* const* d_in, const int* in_sizes, int n_in,
                              void* d_out, int out_size, void* d_ws, size_t ws_size,
                              hipStream_t stream) {
    const float* x    = (const float*)d_in[0];
    const int*   esrc = (const int*)  d_in[1];
    const int*   edst = (const int*)  d_in[2];
    const float* eval = (const float*)d_in[3];
    const float* W1   = (const float*)d_in[4];
    const float* b1   = (const float*)d_in[5];
    const float* W2   = (const float*)d_in[6];
    const float* b2   = (const float*)d_in[7];
    float* out = (float*)d_out;

    const int N = in_sizes[0] / F;
    const int R = in_sizes[4] / (F * F);
    const int E = in_sizes[1] / R;
    const int RE = R * E;
    const int RN = R * N;
    const int nrb = (N + BM - 1) / BM;
    const int Mp = nrb * BM;
    const int nwg = nrb * (F / BN);            // 782 for N=50000

    // ---- workspace layout ----
    char* ws = (char*)d_ws;
    unsigned short* Y = (unsigned short*)ws;             // [Mp][1024] bf16
    ws += (size_t)Mp * KC * sizeof(unsigned short);
    unsigned short* xb = (unsigned short*)ws;            // [N][256] bf16
    ws += (size_t)N * F * sizeof(unsigned short);
    unsigned short* x1b = (unsigned short*)ws;           // [N][256] bf16
    ws += (size_t)N * F * sizeof(unsigned short);
    unsigned short* WTc1 = (unsigned short*)ws;          // [256][1024] bf16
    ws += (size_t)F * KC * sizeof(unsigned short);
    unsigned short* WTc2 = (unsigned short*)ws;
    ws += (size_t)F * KC * sizeof(unsigned short);
    int2* epack = (int2*)ws;                             // [R*E]
    ws += (size_t)RE * sizeof(int2);
    int* row_ptr = (int*)ws;                             // [R*N + 1]
    ws += (size_t)(RN + 1) * sizeof(int);
    int* cursor = (int*)ws;                              // [R*N]
    ws += (size_t)RN * sizeof(int);
    int* bsum = (int*)ws;

    // ---- CSR build (once; reused by both layers) ----
    hipMemsetAsync(row_ptr, 0, (size_t)(RN + 1) * sizeof(int), stream);
    count_kern<<<(RE + 255) / 256, 256, 0, stream>>>(edst, row_ptr, RE, E, N);
    const int nb_scan = (RN + SCAN_ELEMS - 1) / SCAN_ELEMS;
    scan1_kern<<<nb_scan, SCAN_T, 0, stream>>>(row_ptr, bsum, RN);
    scan2_kern<<<1, SCAN_T, 0, stream>>>(bsum, nb_scan);
    scan3_kern<<<(RN + 1 + 255) / 256, 256, 0, stream>>>(row_ptr, bsum, cursor, RN, RE);
    fill_kern<<<(RE + 255) / 256, 256, 0, stream>>>(esrc, edst, eval, cursor, epack, RE, E, N);

    // ---- weight transpose+convert (once) ----
    dim3 tgrid(F / 32, F / 32, R);
    transpose_wcat<<<tgrid, 256, 0, stream>>>(W1, WTc1);
    transpose_wcat<<<tgrid, 256, 0, stream>>>(W2, WTc2);

    // ---- input conversion (once) ----
    convert_bf16<<<(N * (F / 8) + 255) / 256, 256, 0, stream>>>(x, xb, N * (F / 8));

    // layer 1: Y = gather(xb); out/x1b = relu(Y @ Wc1 + b1)
    aggregate_g<<<N, 256, 0, stream>>>(xb, row_ptr, epack, Y, N);
    gemm_fused<false><<<nwg, 256, 0, stream>>>(Y, WTc1, b1, out, x1b, N, nwg);

    // layer 2: Y = gather(x1b); out = relu(Y @ Wc2 + b2) + out
    aggregate_g<<<N, 256, 0, stream>>>(x1b, row_ptr, epack, Y, N);
    gemm_fused<true><<<nwg, 256, 0, stream>>>(Y, WTc2, b2, out, x1b, N, nwg);
}

// Round 8
// 562.767 us; speedup vs baseline: 20.1891x; 1.0120x over previous
//
#include <hip/hip_runtime.h>
#include <hip/hip_bf16.h>

#define F 256
#define KC 1024           // concatenated K = R * F
#define BM 128
#define BN 128
#define BK 32
#define SCAN_T 256
#define SCAN_ELEMS 1024

typedef __attribute__((ext_vector_type(8))) short bf16x8;
typedef __attribute__((ext_vector_type(4))) float f32x4;
typedef __attribute__((address_space(3))) unsigned int* lds_u32p;
typedef const __attribute__((address_space(1))) unsigned int* glb_u32p;

__device__ __forceinline__ float bf2f(unsigned short u) {
    return __uint_as_float((unsigned)u << 16);
}
__device__ __forceinline__ unsigned short f2bf(float x) {
    return __bfloat16_as_ushort(__float2bfloat16(x));
}

// ---------------- convert fp32 [N][256] -> bf16 [N][256] ----------------
__global__ __launch_bounds__(256) void convert_bf16(const float* __restrict__ in,
                                                    unsigned short* __restrict__ outb,
                                                    int total8) {
    int i = blockIdx.x * 256 + threadIdx.x;
    if (i >= total8) return;
    const float* p = in + (size_t)i * 8;
    float4 a = *(const float4*)p;
    float4 b = *(const float4*)(p + 4);
    bf16x8 v;
    v[0] = f2bf(a.x); v[1] = f2bf(a.y); v[2] = f2bf(a.z); v[3] = f2bf(a.w);
    v[4] = f2bf(b.x); v[5] = f2bf(b.y); v[6] = f2bf(b.z); v[7] = f2bf(b.w);
    *(bf16x8*)(outb + (size_t)i * 8) = v;
}

// ---- W [R][256(k)][256(c)] fp32 -> WT [256(c)][1024(r*256+k)] bf16 ----
// blockIdx.z in [0, 2R): low 2 bits = relation, bit 2 = which weight tensor.
__global__ __launch_bounds__(256) void transpose_wcat2(const float* __restrict__ W1,
                                                       const float* __restrict__ W2,
                                                       unsigned short* __restrict__ WT1,
                                                       unsigned short* __restrict__ WT2,
                                                       int R) {
    __shared__ float t[32][33];
    const int z = blockIdx.z;
    const int rel = z % R;
    const float* Wr = (z < R ? W1 : W2) + (size_t)rel * F * F;
    unsigned short* WT = (z < R ? WT1 : WT2);
    const int k0 = blockIdx.x * 32, c0 = blockIdx.y * 32;
    const int tx = threadIdx.x & 31, ty = threadIdx.x >> 5;
#pragma unroll
    for (int i = 0; i < 32; i += 8)
        t[ty + i][tx] = Wr[(size_t)(k0 + ty + i) * F + c0 + tx];
    __syncthreads();
#pragma unroll
    for (int i = 0; i < 32; i += 8)
        WT[(size_t)(c0 + ty + i) * KC + rel * F + k0 + tx] = f2bf(t[tx][ty + i]);
}

// ---------------- CSR build ----------------
__global__ __launch_bounds__(256) void count_kern(const int* __restrict__ edst,
                                                  int* __restrict__ counts,
                                                  int total, int E, int Nn) {
    int i = blockIdx.x * blockDim.x + threadIdx.x;
    if (i >= total) return;
    int r = i / E;
    atomicAdd(counts + r * Nn + edst[i], 1);
}

__global__ __launch_bounds__(SCAN_T) void scan1_kern(int* __restrict__ data,
                                                     int* __restrict__ bsum, int n) {
    __shared__ int sh[SCAN_T];
    const int t = threadIdx.x;
    const int base = blockIdx.x * SCAN_ELEMS + t * 4;
    int v[4];
    int tsum = 0;
#pragma unroll
    for (int j = 0; j < 4; ++j) {
        v[j] = (base + j < n) ? data[base + j] : 0;
        tsum += v[j];
    }
    sh[t] = tsum;
    __syncthreads();
    for (int off = 1; off < SCAN_T; off <<= 1) {
        int x = (t >= off) ? sh[t - off] : 0;
        __syncthreads();
        sh[t] += x;
        __syncthreads();
    }
    if (t == SCAN_T - 1) bsum[blockIdx.x] = sh[t];
    int run = sh[t] - tsum;
#pragma unroll
    for (int j = 0; j < 4; ++j) {
        if (base + j < n) data[base + j] = run;
        run += v[j];
    }
}

__global__ __launch_bounds__(SCAN_T) void scan2_kern(int* __restrict__ bsum, int nb) {
    __shared__ int sh[SCAN_T];
    const int t = threadIdx.x;
    int val = (t < nb) ? bsum[t] : 0;
    sh[t] = val;
    __syncthreads();
    for (int off = 1; off < SCAN_T; off <<= 1) {
        int x = (t >= off) ? sh[t - off] : 0;
        __syncthreads();
        sh[t] += x;
        __syncthreads();
    }
    if (t < nb) bsum[t] = sh[t] - val;
}

__global__ __launch_bounds__(256) void scan3_kern(int* __restrict__ row_ptr,
                                                  const int* __restrict__ bsum,
                                                  int* __restrict__ cursor,
                                                  int n, int total) {
    int i = blockIdx.x * blockDim.x + threadIdx.x;
    if (i < n) {
        int v = row_ptr[i] + bsum[i >> 10];
        row_ptr[i] = v;
        cursor[i] = v;
    } else if (i == n) {
        row_ptr[n] = total;
    }
}

__global__ __launch_bounds__(256) void fill_kern(const int* __restrict__ esrc,
                                                 const int* __restrict__ edst,
                                                 const float* __restrict__ eval,
                                                 int* __restrict__ cursor,
                                                 int2* __restrict__ epack,
                                                 int total, int E, int Nn) {
    int i = blockIdx.x * blockDim.x + threadIdx.x;
    if (i >= total) return;
    int r = i / E;
    int key = r * Nn + edst[i];
    int pos = atomicAdd(cursor + key, 1);
    epack[pos] = make_int2(esrc[i], __float_as_int(eval[i]));
}

// ---------------- Gather-aggregate on input features ----------------
// Y[d][r*256 + f] = sum_{e in CSR(r,d)} val_e * xb[src_e][f]; one wave per (d,r)
// 8-deep software pipeline (avg run length = 8 edges).
__global__ __launch_bounds__(256) void aggregate_g(const unsigned short* __restrict__ xb,
                                                   const int* __restrict__ row_ptr,
                                                   const int2* __restrict__ epack,
                                                   unsigned short* __restrict__ Y,
                                                   int Nn) {
    const int d = blockIdx.x;
    const int r = threadIdx.x >> 6;
    if (d >= Nn) return;
    const int lane4 = (threadIdx.x & 63) * 4;

    const int key = r * Nn + d;
    int e = row_ptr[key];
    const int end = row_ptr[key + 1];

    float4 acc = make_float4(0.f, 0.f, 0.f, 0.f);
    // 8-deep: 8 independent epack + gather loads in flight
    for (; e + 8 <= end; e += 8) {
        int2 p0 = epack[e + 0]; int2 p1 = epack[e + 1];
        int2 p2 = epack[e + 2]; int2 p3 = epack[e + 3];
        int2 p4 = epack[e + 4]; int2 p5 = epack[e + 5];
        int2 p6 = epack[e + 6]; int2 p7 = epack[e + 7];
        ushort4 h0 = *(const ushort4*)(xb + (size_t)p0.x * F + lane4);
        ushort4 h1 = *(const ushort4*)(xb + (size_t)p1.x * F + lane4);
        ushort4 h2 = *(const ushort4*)(xb + (size_t)p2.x * F + lane4);
        ushort4 h3 = *(const ushort4*)(xb + (size_t)p3.x * F + lane4);
        ushort4 h4 = *(const ushort4*)(xb + (size_t)p4.x * F + lane4);
        ushort4 h5 = *(const ushort4*)(xb + (size_t)p5.x * F + lane4);
        ushort4 h6 = *(const ushort4*)(xb + (size_t)p6.x * F + lane4);
        ushort4 h7 = *(const ushort4*)(xb + (size_t)p7.x * F + lane4);
        const float v0 = __int_as_float(p0.y), v1 = __int_as_float(p1.y);
        const float v2 = __int_as_float(p2.y), v3 = __int_as_float(p3.y);
        const float v4 = __int_as_float(p4.y), v5 = __int_as_float(p5.y);
        const float v6 = __int_as_float(p6.y), v7 = __int_as_float(p7.y);
        acc.x = fmaf(bf2f(h0.x), v0, acc.x); acc.y = fmaf(bf2f(h0.y), v0, acc.y);
        acc.z = fmaf(bf2f(h0.z), v0, acc.z); acc.w = fmaf(bf2f(h0.w), v0, acc.w);
        acc.x = fmaf(bf2f(h1.x), v1, acc.x); acc.y = fmaf(bf2f(h1.y), v1, acc.y);
        acc.z = fmaf(bf2f(h1.z), v1, acc.z); acc.w = fmaf(bf2f(h1.w), v1, acc.w);
        acc.x = fmaf(bf2f(h2.x), v2, acc.x); acc.y = fmaf(bf2f(h2.y), v2, acc.y);
        acc.z = fmaf(bf2f(h2.z), v2, acc.z); acc.w = fmaf(bf2f(h2.w), v2, acc.w);
        acc.x = fmaf(bf2f(h3.x), v3, acc.x); acc.y = fmaf(bf2f(h3.y), v3, acc.y);
        acc.z = fmaf(bf2f(h3.z), v3, acc.z); acc.w = fmaf(bf2f(h3.w), v3, acc.w);
        acc.x = fmaf(bf2f(h4.x), v4, acc.x); acc.y = fmaf(bf2f(h4.y), v4, acc.y);
        acc.z = fmaf(bf2f(h4.z), v4, acc.z); acc.w = fmaf(bf2f(h4.w), v4, acc.w);
        acc.x = fmaf(bf2f(h5.x), v5, acc.x); acc.y = fmaf(bf2f(h5.y), v5, acc.y);
        acc.z = fmaf(bf2f(h5.z), v5, acc.z); acc.w = fmaf(bf2f(h5.w), v5, acc.w);
        acc.x = fmaf(bf2f(h6.x), v6, acc.x); acc.y = fmaf(bf2f(h6.y), v6, acc.y);
        acc.z = fmaf(bf2f(h6.z), v6, acc.z); acc.w = fmaf(bf2f(h6.w), v6, acc.w);
        acc.x = fmaf(bf2f(h7.x), v7, acc.x); acc.y = fmaf(bf2f(h7.y), v7, acc.y);
        acc.z = fmaf(bf2f(h7.z), v7, acc.z); acc.w = fmaf(bf2f(h7.w), v7, acc.w);
    }
    for (; e + 4 <= end; e += 4) {
        int2 p0 = epack[e + 0]; int2 p1 = epack[e + 1];
        int2 p2 = epack[e + 2]; int2 p3 = epack[e + 3];
        ushort4 h0 = *(const ushort4*)(xb + (size_t)p0.x * F + lane4);
        ushort4 h1 = *(const ushort4*)(xb + (size_t)p1.x * F + lane4);
        ushort4 h2 = *(const ushort4*)(xb + (size_t)p2.x * F + lane4);
        ushort4 h3 = *(const ushort4*)(xb + (size_t)p3.x * F + lane4);
        const float v0 = __int_as_float(p0.y), v1 = __int_as_float(p1.y);
        const float v2 = __int_as_float(p2.y), v3 = __int_as_float(p3.y);
        acc.x = fmaf(bf2f(h0.x), v0, acc.x); acc.y = fmaf(bf2f(h0.y), v0, acc.y);
        acc.z = fmaf(bf2f(h0.z), v0, acc.z); acc.w = fmaf(bf2f(h0.w), v0, acc.w);
        acc.x = fmaf(bf2f(h1.x), v1, acc.x); acc.y = fmaf(bf2f(h1.y), v1, acc.y);
        acc.z = fmaf(bf2f(h1.z), v1, acc.z); acc.w = fmaf(bf2f(h1.w), v1, acc.w);
        acc.x = fmaf(bf2f(h2.x), v2, acc.x); acc.y = fmaf(bf2f(h2.y), v2, acc.y);
        acc.z = fmaf(bf2f(h2.z), v2, acc.z); acc.w = fmaf(bf2f(h2.w), v2, acc.w);
        acc.x = fmaf(bf2f(h3.x), v3, acc.x); acc.y = fmaf(bf2f(h3.y), v3, acc.y);
        acc.z = fmaf(bf2f(h3.z), v3, acc.z); acc.w = fmaf(bf2f(h3.w), v3, acc.w);
    }
    for (; e < end; ++e) {
        int2 p = epack[e];
        const float v = __int_as_float(p.y);
        ushort4 hv = *(const ushort4*)(xb + (size_t)p.x * F + lane4);
        acc.x = fmaf(bf2f(hv.x), v, acc.x);
        acc.y = fmaf(bf2f(hv.y), v, acc.y);
        acc.z = fmaf(bf2f(hv.z), v, acc.z);
        acc.w = fmaf(bf2f(hv.w), v, acc.w);
    }
    ushort4 o;
    o.x = f2bf(acc.x); o.y = f2bf(acc.y); o.z = f2bf(acc.z); o.w = f2bf(acc.w);
    *(ushort4*)(Y + (size_t)d * KC + r * F + lane4) = o;
}

// ---------------- LDS-staged MFMA GEMM + fused epilogue (m97 structure) --------
// C = Y[Mp,1024] @ WT^T  (WT: [256 cols][1024 k] bf16)
// LAYER1: out = relu(C+b) fp32; x1b = bf16(same)
// LAYER2: out = relu(C+b) + out
template <bool LAYER2>
__global__ __launch_bounds__(256) void gemm_fused(const unsigned short* __restrict__ A,
                                                  const unsigned short* __restrict__ WT,
                                                  const float* __restrict__ bias,
                                                  float* __restrict__ out,
                                                  unsigned short* __restrict__ x1b,
                                                  int Nn, int nwg) {
    __shared__ unsigned short As[BM][BK];   // 8 KB, linear row-major (64 B rows)
    __shared__ unsigned short Bs[BN][BK];   // 8 KB

    // bijective XCD swizzle (m204): consecutive swz share an A row-panel per XCD
    const int xcd = blockIdx.x % 8;
    const int j = blockIdx.x / 8;
    const int q = nwg / 8, rr = nwg % 8;
    const int swz = (xcd < rr ? xcd * (q + 1) : rr * (q + 1) + (xcd - rr) * q) + j;
    const int rb = swz >> 1;
    const int cb = swz & 1;

    const int tid = threadIdx.x;
    const int wave = tid >> 6, lane = tid & 63;
    const int wr = wave >> 1, wc = wave & 1;
    const int row0 = rb * BM;
    const int col0 = cb * BN;

    const int lrow = lane & 15, lk8 = (lane >> 4) * 8;

    // staging: each global_load_lds call moves 256 thr x 16 B = 64 rows x 64 B
    const int srow = wave * 16 + (lane >> 2);   // + i*64
    const int scol = (lane & 3) * 8;            // element offset in k

    f32x4 acc[4][4] = {};

    for (int k0 = 0; k0 < KC; k0 += BK) {
#pragma unroll
        for (int i = 0; i < 2; ++i) {
            const unsigned short* gA = A + (size_t)(row0 + i * 64 + srow) * KC + k0 + scol;
            __builtin_amdgcn_global_load_lds((glb_u32p)gA,
                (lds_u32p)&As[i * 64 + wave * 16][0], 16, 0, 0);
        }
#pragma unroll
        for (int i = 0; i < 2; ++i) {
            const unsigned short* gB = WT + (size_t)(col0 + i * 64 + srow) * KC + k0 + scol;
            __builtin_amdgcn_global_load_lds((glb_u32p)gB,
                (lds_u32p)&Bs[i * 64 + wave * 16][0], 16, 0, 0);
        }
        __syncthreads();

        bf16x8 a[4], b[4];
#pragma unroll
        for (int m = 0; m < 4; ++m)
            a[m] = *(const bf16x8*)&As[wr * 64 + m * 16 + lrow][lk8];
#pragma unroll
        for (int n = 0; n < 4; ++n)
            b[n] = *(const bf16x8*)&Bs[wc * 64 + n * 16 + lrow][lk8];
#pragma unroll
        for (int m = 0; m < 4; ++m)
#pragma unroll
            for (int n = 0; n < 4; ++n)
                acc[m][n] = __builtin_amdgcn_mfma_f32_16x16x32_bf16(a[m], b[n], acc[m][n], 0, 0, 0);
        __syncthreads();
    }

    // C/D layout: col = lane&15, row = (lane>>4)*4 + q  [m89/m91]
    const int crow = (lane >> 4) * 4;
    const int ccol = lane & 15;
#pragma unroll
    for (int m = 0; m < 4; ++m) {
#pragma unroll
        for (int q4 = 0; q4 < 4; ++q4) {
            const int grow = row0 + wr * 64 + m * 16 + crow + q4;
            if (grow >= Nn) continue;
#pragma unroll
            for (int n = 0; n < 4; ++n) {
                const int gcol = col0 + wc * 64 + n * 16 + ccol;
                float v = acc[m][n][q4] + bias[gcol];
                v = fmaxf(v, 0.f);
                const size_t oi = (size_t)grow * F + gcol;
                if (LAYER2) {
                    out[oi] = v + out[oi];
                } else {
                    out[oi] = v;
                    x1b[oi] = f2bf(v);
                }
            }
        }
    }
}

extern "C" void kernel_launch(void* const* d_in, const int* in_sizes, int n_in,
                              void* d_out, int out_size, void* d_ws, size_t ws_size,
                              hipStream_t stream) {
    const float* x    = (const float*)d_in[0];
    const int*   esrc = (const int*)  d_in[1];
    const int*   edst = (const int*)  d_in[2];
    const float* eval = (const float*)d_in[3];
    const float* W1   = (const float*)d_in[4];
    const float* b1   = (const float*)d_in[5];
    const float* W2   = (const float*)d_in[6];
    const float* b2   = (const float*)d_in[7];
    float* out = (float*)d_out;

    const int N = in_sizes[0] / F;
    const int R = in_sizes[4] / (F * F);
    const int E = in_sizes[1] / R;
    const int RE = R * E;
    const int RN = R * N;
    const int nrb = (N + BM - 1) / BM;
    const int Mp = nrb * BM;
    const int nwg = nrb * (F / BN);            // 782 for N=50000

    // ---- workspace layout ----
    char* ws = (char*)d_ws;
    unsigned short* Y = (unsigned short*)ws;             // [Mp][1024] bf16
    ws += (size_t)Mp * KC * sizeof(unsigned short);
    unsigned short* xb = (unsigned short*)ws;            // [N][256] bf16
    ws += (size_t)N * F * sizeof(unsigned short);
    unsigned short* x1b = (unsigned short*)ws;           // [N][256] bf16
    ws += (size_t)N * F * sizeof(unsigned short);
    unsigned short* WTc1 = (unsigned short*)ws;          // [256][1024] bf16
    ws += (size_t)F * KC * sizeof(unsigned short);
    unsigned short* WTc2 = (unsigned short*)ws;
    ws += (size_t)F * KC * sizeof(unsigned short);
    int2* epack = (int2*)ws;                             // [R*E]
    ws += (size_t)RE * sizeof(int2);
    int* row_ptr = (int*)ws;                             // [R*N + 1]
    ws += (size_t)(RN + 1) * sizeof(int);
    int* cursor = (int*)ws;                              // [R*N]
    ws += (size_t)RN * sizeof(int);
    int* bsum = (int*)ws;

    // ---- CSR build (once; reused by both layers) ----
    hipMemsetAsync(row_ptr, 0, (size_t)(RN + 1) * sizeof(int), stream);
    count_kern<<<(RE + 255) / 256, 256, 0, stream>>>(edst, row_ptr, RE, E, N);
    const int nb_scan = (RN + SCAN_ELEMS - 1) / SCAN_ELEMS;
    scan1_kern<<<nb_scan, SCAN_T, 0, stream>>>(row_ptr, bsum, RN);
    scan2_kern<<<1, SCAN_T, 0, stream>>>(bsum, nb_scan);
    scan3_kern<<<(RN + 1 + 255) / 256, 256, 0, stream>>>(row_ptr, bsum, cursor, RN, RE);
    fill_kern<<<(RE + 255) / 256, 256, 0, stream>>>(esrc, edst, eval, cursor, epack, RE, E, N);

    // ---- weight transpose+convert (one merged launch) ----
    dim3 tgrid(F / 32, F / 32, 2 * R);
    transpose_wcat2<<<tgrid, 256, 0, stream>>>(W1, W2, WTc1, WTc2, R);

    // ---- input conversion (once) ----
    convert_bf16<<<(N * (F / 8) + 255) / 256, 256, 0, stream>>>(x, xb, N * (F / 8));

    // layer 1: Y = gather(xb); out/x1b = relu(Y @ Wc1 + b1)
    aggregate_g<<<N, 256, 0, stream>>>(xb, row_ptr, epack, Y, N);
    gemm_fused<false><<<nwg, 256, 0, stream>>>(Y, WTc1, b1, out, x1b, N, nwg);

    // layer 2: Y = gather(x1b); out = relu(Y @ Wc2 + b2) + out
    aggregate_g<<<N, 256, 0, stream>>>(x1b, row_ptr, epack, Y, N);
    gemm_fused<true><<<nwg, 256, 0, stream>>>(Y, WTc2, b2, out, x1b, N, nwg);
}

// Round 9
// 532.153 us; speedup vs baseline: 21.3505x; 1.0575x over previous
//
#include <hip/hip_runtime.h>
#include <hip/hip_bf16.h>

#define F 256
#define KC 1024           // concatenated K = R * F
#define BM 128
#define BN 256
#define BK 32
#define SCAN_T 256
#define SCAN_ELEMS 1024

typedef __attribute__((ext_vector_type(8))) short bf16x8;
typedef __attribute__((ext_vector_type(4))) float f32x4;
typedef __attribute__((address_space(3))) unsigned int* lds_u32p;
typedef const __attribute__((address_space(1))) unsigned int* glb_u32p;

__device__ __forceinline__ float bf2f(unsigned short u) {
    return __uint_as_float((unsigned)u << 16);
}
__device__ __forceinline__ unsigned short f2bf(float x) {
    return __bfloat16_as_ushort(__float2bfloat16(x));
}

// ---------------- convert fp32 [N][256] -> bf16 [N][256] ----------------
__global__ __launch_bounds__(256) void convert_bf16(const float* __restrict__ in,
                                                    unsigned short* __restrict__ outb,
                                                    int total8) {
    int i = blockIdx.x * 256 + threadIdx.x;
    if (i >= total8) return;
    const float* p = in + (size_t)i * 8;
    float4 a = *(const float4*)p;
    float4 b = *(const float4*)(p + 4);
    bf16x8 v;
    v[0] = f2bf(a.x); v[1] = f2bf(a.y); v[2] = f2bf(a.z); v[3] = f2bf(a.w);
    v[4] = f2bf(b.x); v[5] = f2bf(b.y); v[6] = f2bf(b.z); v[7] = f2bf(b.w);
    *(bf16x8*)(outb + (size_t)i * 8) = v;
}

// ---- W [R][256(k)][256(c)] fp32 -> WT [256(c)][1024(r*256+k)] bf16 ----
__global__ __launch_bounds__(256) void transpose_wcat2(const float* __restrict__ W1,
                                                       const float* __restrict__ W2,
                                                       unsigned short* __restrict__ WT1,
                                                       unsigned short* __restrict__ WT2,
                                                       int R) {
    __shared__ float t[32][33];
    const int z = blockIdx.z;
    const int rel = z % R;
    const float* Wr = (z < R ? W1 : W2) + (size_t)rel * F * F;
    unsigned short* WT = (z < R ? WT1 : WT2);
    const int k0 = blockIdx.x * 32, c0 = blockIdx.y * 32;
    const int tx = threadIdx.x & 31, ty = threadIdx.x >> 5;
#pragma unroll
    for (int i = 0; i < 32; i += 8)
        t[ty + i][tx] = Wr[(size_t)(k0 + ty + i) * F + c0 + tx];
    __syncthreads();
#pragma unroll
    for (int i = 0; i < 32; i += 8)
        WT[(size_t)(c0 + ty + i) * KC + rel * F + k0 + tx] = f2bf(t[tx][ty + i]);
}

// ---------------- CSR build ----------------
__global__ __launch_bounds__(256) void count_kern(const int* __restrict__ edst,
                                                  int* __restrict__ counts,
                                                  int total, int E, int Nn) {
    int i = blockIdx.x * blockDim.x + threadIdx.x;
    if (i >= total) return;
    int r = i / E;
    atomicAdd(counts + r * Nn + edst[i], 1);
}

__global__ __launch_bounds__(SCAN_T) void scan1_kern(int* __restrict__ data,
                                                     int* __restrict__ bsum, int n) {
    __shared__ int sh[SCAN_T];
    const int t = threadIdx.x;
    const int base = blockIdx.x * SCAN_ELEMS + t * 4;
    int v[4];
    int tsum = 0;
#pragma unroll
    for (int j = 0; j < 4; ++j) {
        v[j] = (base + j < n) ? data[base + j] : 0;
        tsum += v[j];
    }
    sh[t] = tsum;
    __syncthreads();
    for (int off = 1; off < SCAN_T; off <<= 1) {
        int x = (t >= off) ? sh[t - off] : 0;
        __syncthreads();
        sh[t] += x;
        __syncthreads();
    }
    if (t == SCAN_T - 1) bsum[blockIdx.x] = sh[t];
    int run = sh[t] - tsum;
#pragma unroll
    for (int j = 0; j < 4; ++j) {
        if (base + j < n) data[base + j] = run;
        run += v[j];
    }
}

__global__ __launch_bounds__(SCAN_T) void scan2_kern(int* __restrict__ bsum, int nb) {
    __shared__ int sh[SCAN_T];
    const int t = threadIdx.x;
    int val = (t < nb) ? bsum[t] : 0;
    sh[t] = val;
    __syncthreads();
    for (int off = 1; off < SCAN_T; off <<= 1) {
        int x = (t >= off) ? sh[t - off] : 0;
        __syncthreads();
        sh[t] += x;
        __syncthreads();
    }
    if (t < nb) bsum[t] = sh[t] - val;
}

__global__ __launch_bounds__(256) void scan3_kern(int* __restrict__ row_ptr,
                                                  const int* __restrict__ bsum,
                                                  int* __restrict__ cursor,
                                                  int n, int total) {
    int i = blockIdx.x * blockDim.x + threadIdx.x;
    if (i < n) {
        int v = row_ptr[i] + bsum[i >> 10];
        row_ptr[i] = v;
        cursor[i] = v;
    } else if (i == n) {
        row_ptr[n] = total;
    }
}

__global__ __launch_bounds__(256) void fill_kern(const int* __restrict__ esrc,
                                                 const int* __restrict__ edst,
                                                 const float* __restrict__ eval,
                                                 int* __restrict__ cursor,
                                                 int2* __restrict__ epack,
                                                 int total, int E, int Nn) {
    int i = blockIdx.x * blockDim.x + threadIdx.x;
    if (i >= total) return;
    int r = i / E;
    int key = r * Nn + edst[i];
    int pos = atomicAdd(cursor + key, 1);
    epack[pos] = make_int2(esrc[i], __float_as_int(eval[i]));
}

// ---------------- Gather-aggregate: 2 edges per wave, 16 B/lane ----------------
// Y[d][r*256 + f] = sum_{e in CSR(r,d)} val_e * xb[src_e][f]
// wave = one (d, r) run; lanes 0-31 edge A (8 feats/lane), lanes 32-63 edge B.
__global__ __launch_bounds__(256) void aggregate_g(const unsigned short* __restrict__ xb,
                                                   const int* __restrict__ row_ptr,
                                                   const int2* __restrict__ epack,
                                                   unsigned short* __restrict__ Y,
                                                   int Nn) {
    const int d = blockIdx.x;
    const int r = threadIdx.x >> 6;
    if (d >= Nn) return;
    const int lane = threadIdx.x & 63;
    const int half = lane >> 5;            // 0: even edge, 1: odd edge
    const int f8 = (lane & 31) * 8;        // 8 features per lane

    const int key = r * Nn + d;
    int e = row_ptr[key];
    const int end = row_ptr[key + 1];

    float acc[8] = {0.f, 0.f, 0.f, 0.f, 0.f, 0.f, 0.f, 0.f};

    // 4 pairs (8 edges) in flight
    for (; e + 8 <= end; e += 8) {
        int2 p0 = epack[e + 0 + half];
        int2 p1 = epack[e + 2 + half];
        int2 p2 = epack[e + 4 + half];
        int2 p3 = epack[e + 6 + half];
        bf16x8 h0 = *(const bf16x8*)(xb + (size_t)p0.x * F + f8);
        bf16x8 h1 = *(const bf16x8*)(xb + (size_t)p1.x * F + f8);
        bf16x8 h2 = *(const bf16x8*)(xb + (size_t)p2.x * F + f8);
        bf16x8 h3 = *(const bf16x8*)(xb + (size_t)p3.x * F + f8);
        const float v0 = __int_as_float(p0.y), v1 = __int_as_float(p1.y);
        const float v2 = __int_as_float(p2.y), v3 = __int_as_float(p3.y);
#pragma unroll
        for (int j = 0; j < 8; ++j) acc[j] = fmaf(bf2f((unsigned short)h0[j]), v0, acc[j]);
#pragma unroll
        for (int j = 0; j < 8; ++j) acc[j] = fmaf(bf2f((unsigned short)h1[j]), v1, acc[j]);
#pragma unroll
        for (int j = 0; j < 8; ++j) acc[j] = fmaf(bf2f((unsigned short)h2[j]), v2, acc[j]);
#pragma unroll
        for (int j = 0; j < 8; ++j) acc[j] = fmaf(bf2f((unsigned short)h3[j]), v3, acc[j]);
    }
    for (; e + 2 <= end; e += 2) {
        int2 p = epack[e + half];
        const float v = __int_as_float(p.y);
        bf16x8 h = *(const bf16x8*)(xb + (size_t)p.x * F + f8);
#pragma unroll
        for (int j = 0; j < 8; ++j) acc[j] = fmaf(bf2f((unsigned short)h[j]), v, acc[j]);
    }
    if (e < end) {                         // single leftover edge: half 1 contributes 0
        int2 p = epack[e];
        const float v = half == 0 ? __int_as_float(p.y) : 0.f;
        bf16x8 h = *(const bf16x8*)(xb + (size_t)p.x * F + f8);
#pragma unroll
        for (int j = 0; j < 8; ++j) acc[j] = fmaf(bf2f((unsigned short)h[j]), v, acc[j]);
    }

    // combine edge-A/edge-B halves (lane l <-> l+32)
#pragma unroll
    for (int j = 0; j < 8; ++j) acc[j] += __shfl_xor(acc[j], 32);

    if (half == 0) {
        bf16x8 o;
#pragma unroll
        for (int j = 0; j < 8; ++j) o[j] = (short)f2bf(acc[j]);
        *(bf16x8*)(Y + (size_t)d * KC + r * F + f8) = o;
    }
}

// ---------------- LDS-staged MFMA GEMM, BN=256 (single col pass) --------------
// C = Y[Mp,1024] @ WT^T  (WT: [256 cols][1024 k] bf16); 512 thr, 8 waves (2x4).
// LAYER1: out = relu(C+b) fp32; x1b = bf16(same).  LAYER2: out = relu(C+b)+out.
template <bool LAYER2>
__global__ __launch_bounds__(512) void gemm_fused(const unsigned short* __restrict__ A,
                                                  const unsigned short* __restrict__ WT,
                                                  const float* __restrict__ bias,
                                                  float* __restrict__ out,
                                                  unsigned short* __restrict__ x1b,
                                                  int Nn, int nwg) {
    __shared__ unsigned short As[BM][BK];   // 8 KB
    __shared__ unsigned short Bs[BN][BK];   // 16 KB

    // bijective XCD swizzle (m204)
    const int xcd = blockIdx.x % 8;
    const int j = blockIdx.x / 8;
    const int q = nwg / 8, rr = nwg % 8;
    const int rb = (xcd < rr ? xcd * (q + 1) : rr * (q + 1) + (xcd - rr) * q) + j;
    const int row0 = rb * BM;

    const int tid = threadIdx.x;
    const int wave = tid >> 6, lane = tid & 63;
    const int wr = wave >> 2, wc = wave & 3;     // 2 x 4 wave grid, 64x64 each

    const int lrow = lane & 15, lk8 = (lane >> 4) * 8;

    // staging: 512 thr x 16 B = 128 rows x 64 B per call
    const int srow = tid >> 2;          // 0..127
    const int scol = (tid & 3) * 8;

    f32x4 acc[4][4] = {};

    for (int k0 = 0; k0 < KC; k0 += BK) {
        {
            const unsigned short* gA = A + (size_t)(row0 + srow) * KC + k0 + scol;
            __builtin_amdgcn_global_load_lds((glb_u32p)gA,
                (lds_u32p)&As[wave * 16][0], 16, 0, 0);
        }
#pragma unroll
        for (int i = 0; i < 2; ++i) {
            const unsigned short* gB = WT + (size_t)(i * 128 + srow) * KC + k0 + scol;
            __builtin_amdgcn_global_load_lds((glb_u32p)gB,
                (lds_u32p)&Bs[i * 128 + wave * 16][0], 16, 0, 0);
        }
        __syncthreads();

        bf16x8 a[4], b[4];
#pragma unroll
        for (int m = 0; m < 4; ++m)
            a[m] = *(const bf16x8*)&As[wr * 64 + m * 16 + lrow][lk8];
#pragma unroll
        for (int n = 0; n < 4; ++n)
            b[n] = *(const bf16x8*)&Bs[wc * 64 + n * 16 + lrow][lk8];
#pragma unroll
        for (int m = 0; m < 4; ++m)
#pragma unroll
            for (int n = 0; n < 4; ++n)
                acc[m][n] = __builtin_amdgcn_mfma_f32_16x16x32_bf16(a[m], b[n], acc[m][n], 0, 0, 0);
        __syncthreads();
    }

    // C/D layout: col = lane&15, row = (lane>>4)*4 + q  [m89/m91]
    const int crow = (lane >> 4) * 4;
    const int ccol = lane & 15;
#pragma unroll
    for (int m = 0; m < 4; ++m) {
#pragma unroll
        for (int q4 = 0; q4 < 4; ++q4) {
            const int grow = row0 + wr * 64 + m * 16 + crow + q4;
            if (grow >= Nn) continue;
#pragma unroll
            for (int n = 0; n < 4; ++n) {
                const int gcol = wc * 64 + n * 16 + ccol;
                float v = acc[m][n][q4] + bias[gcol];
                v = fmaxf(v, 0.f);
                const size_t oi = (size_t)grow * F + gcol;
                if (LAYER2) {
                    out[oi] = v + out[oi];
                } else {
                    out[oi] = v;
                    x1b[oi] = f2bf(v);
                }
            }
        }
    }
}

extern "C" void kernel_launch(void* const* d_in, const int* in_sizes, int n_in,
                              void* d_out, int out_size, void* d_ws, size_t ws_size,
                              hipStream_t stream) {
    const float* x    = (const float*)d_in[0];
    const int*   esrc = (const int*)  d_in[1];
    const int*   edst = (const int*)  d_in[2];
    const float* eval = (const float*)d_in[3];
    const float* W1   = (const float*)d_in[4];
    const float* b1   = (const float*)d_in[5];
    const float* W2   = (const float*)d_in[6];
    const float* b2   = (const float*)d_in[7];
    float* out = (float*)d_out;

    const int N = in_sizes[0] / F;
    const int R = in_sizes[4] / (F * F);
    const int E = in_sizes[1] / R;
    const int RE = R * E;
    const int RN = R * N;
    const int nrb = (N + BM - 1) / BM;         // 391 for N=50000
    const int Mp = nrb * BM;
    const int nwg = nrb;                       // BN=256 covers all cols

    // ---- workspace layout ----
    char* ws = (char*)d_ws;
    unsigned short* Y = (unsigned short*)ws;             // [Mp][1024] bf16
    ws += (size_t)Mp * KC * sizeof(unsigned short);
    unsigned short* xb = (unsigned short*)ws;            // [N][256] bf16
    ws += (size_t)N * F * sizeof(unsigned short);
    unsigned short* x1b = (unsigned short*)ws;           // [N][256] bf16
    ws += (size_t)N * F * sizeof(unsigned short);
    unsigned short* WTc1 = (unsigned short*)ws;          // [256][1024] bf16
    ws += (size_t)F * KC * sizeof(unsigned short);
    unsigned short* WTc2 = (unsigned short*)ws;
    ws += (size_t)F * KC * sizeof(unsigned short);
    int2* epack = (int2*)ws;                             // [R*E]
    ws += (size_t)RE * sizeof(int2);
    int* row_ptr = (int*)ws;                             // [R*N + 1]
    ws += (size_t)(RN + 1) * sizeof(int);
    int* cursor = (int*)ws;                              // [R*N]
    ws += (size_t)RN * sizeof(int);
    int* bsum = (int*)ws;

    // ---- CSR build (once; reused by both layers) ----
    hipMemsetAsync(row_ptr, 0, (size_t)(RN + 1) * sizeof(int), stream);
    count_kern<<<(RE + 255) / 256, 256, 0, stream>>>(edst, row_ptr, RE, E, N);
    const int nb_scan = (RN + SCAN_ELEMS - 1) / SCAN_ELEMS;
    scan1_kern<<<nb_scan, SCAN_T, 0, stream>>>(row_ptr, bsum, RN);
    scan2_kern<<<1, SCAN_T, 0, stream>>>(bsum, nb_scan);
    scan3_kern<<<(RN + 1 + 255) / 256, 256, 0, stream>>>(row_ptr, bsum, cursor, RN, RE);
    fill_kern<<<(RE + 255) / 256, 256, 0, stream>>>(esrc, edst, eval, cursor, epack, RE, E, N);

    // ---- weight transpose+convert (one merged launch) ----
    dim3 tgrid(F / 32, F / 32, 2 * R);
    transpose_wcat2<<<tgrid, 256, 0, stream>>>(W1, W2, WTc1, WTc2, R);

    // ---- input conversion (once) ----
    convert_bf16<<<(N * (F / 8) + 255) / 256, 256, 0, stream>>>(x, xb, N * (F / 8));

    // layer 1: Y = gather(xb); out/x1b = relu(Y @ Wc1 + b1)
    aggregate_g<<<N, 256, 0, stream>>>(xb, row_ptr, epack, Y, N);
    gemm_fused<false><<<nwg, 512, 0, stream>>>(Y, WTc1, b1, out, x1b, N, nwg);

    // layer 2: Y = gather(x1b); out = relu(Y @ Wc2 + b2) + out
    aggregate_g<<<N, 256, 0, stream>>>(x1b, row_ptr, epack, Y, N);
    gemm_fused<true><<<nwg, 512, 0, stream>>>(Y, WTc2, b2, out, x1b, N, nwg);
}

// Round 10
// 511.063 us; speedup vs baseline: 22.2316x; 1.0413x over previous
//
#include <hip/hip_runtime.h>
#include <hip/hip_bf16.h>
#include <hip/hip_fp16.h>

#define F 256
#define KC 1024           // concatenated K = R * F
#define BM 128
#define BN 256
#define BK 32
#define NT (KC / BK)      // 32 K-steps
#define SCAN_T 256
#define SCAN_ELEMS 1024

typedef __attribute__((ext_vector_type(8))) short bf16x8;
typedef __attribute__((ext_vector_type(4))) float f32x4;
typedef __attribute__((address_space(3))) unsigned int* lds_u32p;
typedef const __attribute__((address_space(1))) unsigned int* glb_u32p;

__device__ __forceinline__ float bf2f(unsigned short u) {
    return __uint_as_float((unsigned)u << 16);
}
__device__ __forceinline__ unsigned short f2bf(float x) {
    return __bfloat16_as_ushort(__float2bfloat16(x));
}
// epack entry: low 16 = src (N < 65536), high 16 = val as fp16
__device__ __forceinline__ float ep_val(unsigned p) {
    return __half2float(__ushort_as_half((unsigned short)(p >> 16)));
}

// ---------------- convert fp32 [N][256] -> bf16 [N][256] ----------------
__global__ __launch_bounds__(256) void convert_bf16(const float* __restrict__ in,
                                                    unsigned short* __restrict__ outb,
                                                    int total8) {
    int i = blockIdx.x * 256 + threadIdx.x;
    if (i >= total8) return;
    const float* p = in + (size_t)i * 8;
    float4 a = *(const float4*)p;
    float4 b = *(const float4*)(p + 4);
    bf16x8 v;
    v[0] = f2bf(a.x); v[1] = f2bf(a.y); v[2] = f2bf(a.z); v[3] = f2bf(a.w);
    v[4] = f2bf(b.x); v[5] = f2bf(b.y); v[6] = f2bf(b.z); v[7] = f2bf(b.w);
    *(bf16x8*)(outb + (size_t)i * 8) = v;
}

// ---- W [R][256(k)][256(c)] fp32 -> WT [256(c)][1024(r*256+k)] bf16 ----
__global__ __launch_bounds__(256) void transpose_wcat2(const float* __restrict__ W1,
                                                       const float* __restrict__ W2,
                                                       unsigned short* __restrict__ WT1,
                                                       unsigned short* __restrict__ WT2,
                                                       int R) {
    __shared__ float t[32][33];
    const int z = blockIdx.z;
    const int rel = z % R;
    const float* Wr = (z < R ? W1 : W2) + (size_t)rel * F * F;
    unsigned short* WT = (z < R ? WT1 : WT2);
    const int k0 = blockIdx.x * 32, c0 = blockIdx.y * 32;
    const int tx = threadIdx.x & 31, ty = threadIdx.x >> 5;
#pragma unroll
    for (int i = 0; i < 32; i += 8)
        t[ty + i][tx] = Wr[(size_t)(k0 + ty + i) * F + c0 + tx];
    __syncthreads();
#pragma unroll
    for (int i = 0; i < 32; i += 8)
        WT[(size_t)(c0 + ty + i) * KC + rel * F + k0 + tx] = f2bf(t[tx][ty + i]);
}

// ---------------- CSR build ----------------
__global__ __launch_bounds__(256) void count_kern(const int* __restrict__ edst,
                                                  int* __restrict__ counts,
                                                  int total, int E, int Nn) {
    int i = blockIdx.x * blockDim.x + threadIdx.x;
    if (i >= total) return;
    int r = i / E;
    atomicAdd(counts + r * Nn + edst[i], 1);
}

__global__ __launch_bounds__(SCAN_T) void scan1_kern(int* __restrict__ data,
                                                     int* __restrict__ bsum, int n) {
    __shared__ int sh[SCAN_T];
    const int t = threadIdx.x;
    const int base = blockIdx.x * SCAN_ELEMS + t * 4;
    int v[4];
    int tsum = 0;
#pragma unroll
    for (int j = 0; j < 4; ++j) {
        v[j] = (base + j < n) ? data[base + j] : 0;
        tsum += v[j];
    }
    sh[t] = tsum;
    __syncthreads();
    for (int off = 1; off < SCAN_T; off <<= 1) {
        int x = (t >= off) ? sh[t - off] : 0;
        __syncthreads();
        sh[t] += x;
        __syncthreads();
    }
    if (t == SCAN_T - 1) bsum[blockIdx.x] = sh[t];
    int run = sh[t] - tsum;
#pragma unroll
    for (int j = 0; j < 4; ++j) {
        if (base + j < n) data[base + j] = run;
        run += v[j];
    }
}

__global__ __launch_bounds__(SCAN_T) void scan2_kern(int* __restrict__ bsum, int nb) {
    __shared__ int sh[SCAN_T];
    const int t = threadIdx.x;
    int val = (t < nb) ? bsum[t] : 0;
    sh[t] = val;
    __syncthreads();
    for (int off = 1; off < SCAN_T; off <<= 1) {
        int x = (t >= off) ? sh[t - off] : 0;
        __syncthreads();
        sh[t] += x;
        __syncthreads();
    }
    if (t < nb) bsum[t] = sh[t] - val;
}

__global__ __launch_bounds__(256) void scan3_kern(int* __restrict__ row_ptr,
                                                  const int* __restrict__ bsum,
                                                  int* __restrict__ cursor,
                                                  int n, int total) {
    int i = blockIdx.x * blockDim.x + threadIdx.x;
    if (i < n) {
        int v = row_ptr[i] + bsum[i >> 10];
        row_ptr[i] = v;
        cursor[i] = v;
    } else if (i == n) {
        row_ptr[n] = total;
    }
}

__global__ __launch_bounds__(256) void fill_kern(const int* __restrict__ esrc,
                                                 const int* __restrict__ edst,
                                                 const float* __restrict__ eval,
                                                 int* __restrict__ cursor,
                                                 unsigned* __restrict__ epack,
                                                 int total, int E, int Nn) {
    int i = blockIdx.x * blockDim.x + threadIdx.x;
    if (i >= total) return;
    int r = i / E;
    int key = r * Nn + edst[i];
    int pos = atomicAdd(cursor + key, 1);
    unsigned short vb = __half_as_ushort(__float2half_rn(eval[i]));
    epack[pos] = (unsigned)(esrc[i] & 0xffff) | ((unsigned)vb << 16);
}

// ---------------- Gather-aggregate: 2 edges per wave, 16 B/lane ----------------
// Y[d][r*256 + f] = sum_{e in CSR(r,d)} val_e * xb[src_e][f]
// wave = one (d, r) run; lanes 0-31 edge A (8 feats/lane), lanes 32-63 edge B.
__global__ __launch_bounds__(256) void aggregate_g(const unsigned short* __restrict__ xb,
                                                   const int* __restrict__ row_ptr,
                                                   const unsigned* __restrict__ epack,
                                                   unsigned short* __restrict__ Y,
                                                   int Nn) {
    const int d = blockIdx.x;
    const int r = threadIdx.x >> 6;
    if (d >= Nn) return;
    const int lane = threadIdx.x & 63;
    const int half = lane >> 5;            // 0: even edge, 1: odd edge
    const int f8 = (lane & 31) * 8;        // 8 features per lane

    const int key = r * Nn + d;
    int e = row_ptr[key];
    const int end = row_ptr[key + 1];

    float acc[8] = {0.f, 0.f, 0.f, 0.f, 0.f, 0.f, 0.f, 0.f};

    // 4 pairs (8 edges) in flight
    for (; e + 8 <= end; e += 8) {
        unsigned p0 = epack[e + 0 + half];
        unsigned p1 = epack[e + 2 + half];
        unsigned p2 = epack[e + 4 + half];
        unsigned p3 = epack[e + 6 + half];
        bf16x8 h0 = *(const bf16x8*)(xb + (size_t)(p0 & 0xffff) * F + f8);
        bf16x8 h1 = *(const bf16x8*)(xb + (size_t)(p1 & 0xffff) * F + f8);
        bf16x8 h2 = *(const bf16x8*)(xb + (size_t)(p2 & 0xffff) * F + f8);
        bf16x8 h3 = *(const bf16x8*)(xb + (size_t)(p3 & 0xffff) * F + f8);
        const float v0 = ep_val(p0), v1 = ep_val(p1);
        const float v2 = ep_val(p2), v3 = ep_val(p3);
#pragma unroll
        for (int j = 0; j < 8; ++j) acc[j] = fmaf(bf2f((unsigned short)h0[j]), v0, acc[j]);
#pragma unroll
        for (int j = 0; j < 8; ++j) acc[j] = fmaf(bf2f((unsigned short)h1[j]), v1, acc[j]);
#pragma unroll
        for (int j = 0; j < 8; ++j) acc[j] = fmaf(bf2f((unsigned short)h2[j]), v2, acc[j]);
#pragma unroll
        for (int j = 0; j < 8; ++j) acc[j] = fmaf(bf2f((unsigned short)h3[j]), v3, acc[j]);
    }
    for (; e + 2 <= end; e += 2) {
        unsigned p = epack[e + half];
        const float v = ep_val(p);
        bf16x8 h = *(const bf16x8*)(xb + (size_t)(p & 0xffff) * F + f8);
#pragma unroll
        for (int j = 0; j < 8; ++j) acc[j] = fmaf(bf2f((unsigned short)h[j]), v, acc[j]);
    }
    if (e < end) {                         // single leftover edge: half 1 contributes 0
        unsigned p = epack[e];
        const float v = half == 0 ? ep_val(p) : 0.f;
        bf16x8 h = *(const bf16x8*)(xb + (size_t)(p & 0xffff) * F + f8);
#pragma unroll
        for (int j = 0; j < 8; ++j) acc[j] = fmaf(bf2f((unsigned short)h[j]), v, acc[j]);
    }

    // combine edge-A/edge-B halves (lane l <-> l+32)
#pragma unroll
    for (int j = 0; j < 8; ++j) acc[j] += __shfl_xor(acc[j], 32);

    if (half == 0) {
        bf16x8 o;
#pragma unroll
        for (int j = 0; j < 8; ++j) o[j] = (short)f2bf(acc[j]);
        *(bf16x8*)(Y + (size_t)d * KC + r * F + f8) = o;
    }
}

// ---------------- LDS-staged MFMA GEMM, BN=256, 2-phase double-buffer ----------
// C = Y[Mp,1024] @ WT^T  (WT: [256 cols][1024 k] bf16); 512 thr, 8 waves (2x4).
// LAYER1: out = relu(C+b) fp32; x1b = bf16(same).  LAYER2: out = relu(C+b)+out.
template <bool LAYER2>
__global__ __launch_bounds__(512) void gemm_fused(const unsigned short* __restrict__ A,
                                                  const unsigned short* __restrict__ WT,
                                                  const float* __restrict__ bias,
                                                  float* __restrict__ out,
                                                  unsigned short* __restrict__ x1b,
                                                  int Nn, int nwg) {
    __shared__ unsigned short As[2][BM][BK];   // 2 x 8 KB
    __shared__ unsigned short Bs[2][BN][BK];   // 2 x 16 KB

    // bijective XCD swizzle (m204)
    const int xcd = blockIdx.x % 8;
    const int j = blockIdx.x / 8;
    const int q = nwg / 8, rr = nwg % 8;
    const int rb = (xcd < rr ? xcd * (q + 1) : rr * (q + 1) + (xcd - rr) * q) + j;
    const int row0 = rb * BM;

    const int tid = threadIdx.x;
    const int wave = tid >> 6, lane = tid & 63;
    const int wr = wave >> 2, wc = wave & 3;     // 2 x 4 wave grid, 64x64 each

    const int lrow = lane & 15, lk8 = (lane >> 4) * 8;

    // staging: 512 thr x 16 B; srow = tid>>2 covers 128 rows, scol 4x8 elem
    const int srow = tid >> 2;          // 0..127
    const int scol = (tid & 3) * 8;

    f32x4 acc[4][4] = {};

    // STAGE(buf, k0): issue A-tile + B-tile global_load_lds for K-step at k0
#define STAGE(buf, k0)                                                               \
    {                                                                                \
        const unsigned short* gA = A + (size_t)(row0 + srow) * KC + (k0) + scol;     \
        __builtin_amdgcn_global_load_lds((glb_u32p)gA,                               \
            (lds_u32p)&As[buf][wave * 16][0], 16, 0, 0);                             \
        const unsigned short* gB0 = WT + (size_t)srow * KC + (k0) + scol;            \
        __builtin_amdgcn_global_load_lds((glb_u32p)gB0,                              \
            (lds_u32p)&Bs[buf][wave * 16][0], 16, 0, 0);                             \
        const unsigned short* gB1 = WT + (size_t)(128 + srow) * KC + (k0) + scol;    \
        __builtin_amdgcn_global_load_lds((glb_u32p)gB1,                              \
            (lds_u32p)&Bs[buf][128 + wave * 16][0], 16, 0, 0);                       \
    }

#define COMPUTE(buf)                                                                 \
    {                                                                                \
        bf16x8 a[4], b[4];                                                           \
        _Pragma("unroll")                                                            \
        for (int m = 0; m < 4; ++m)                                                  \
            a[m] = *(const bf16x8*)&As[buf][wr * 64 + m * 16 + lrow][lk8];           \
        _Pragma("unroll")                                                            \
        for (int n = 0; n < 4; ++n)                                                  \
            b[n] = *(const bf16x8*)&Bs[buf][wc * 64 + n * 16 + lrow][lk8];           \
        _Pragma("unroll")                                                            \
        for (int m = 0; m < 4; ++m)                                                  \
            _Pragma("unroll")                                                        \
            for (int n = 0; n < 4; ++n)                                              \
                acc[m][n] = __builtin_amdgcn_mfma_f32_16x16x32_bf16(a[m], b[n],      \
                                                                   acc[m][n], 0, 0, 0); \
    }

    STAGE(0, 0)
    __syncthreads();                       // drain prologue stage
    int cur = 0;
#pragma unroll 2
    for (int t = 0; t < NT - 1; ++t) {
        STAGE(cur ^ 1, (t + 1) * BK)       // next tile flies under this tile's MFMA
        COMPUTE(cur)
        __syncthreads();                   // vmcnt(0)+lgkm+barrier: next tile ready
        cur ^= 1;
    }
    COMPUTE(cur)
#undef STAGE
#undef COMPUTE

    // C/D layout: col = lane&15, row = (lane>>4)*4 + q  [m89/m91]
    const int crow = (lane >> 4) * 4;
    const int ccol = lane & 15;
#pragma unroll
    for (int m = 0; m < 4; ++m) {
#pragma unroll
        for (int q4 = 0; q4 < 4; ++q4) {
            const int grow = row0 + wr * 64 + m * 16 + crow + q4;
            if (grow >= Nn) continue;
#pragma unroll
            for (int n = 0; n < 4; ++n) {
                const int gcol = wc * 64 + n * 16 + ccol;
                float v = acc[m][n][q4] + bias[gcol];
                v = fmaxf(v, 0.f);
                const size_t oi = (size_t)grow * F + gcol;
                if (LAYER2) {
                    out[oi] = v + out[oi];
                } else {
                    out[oi] = v;
                    x1b[oi] = f2bf(v);
                }
            }
        }
    }
}

extern "C" void kernel_launch(void* const* d_in, const int* in_sizes, int n_in,
                              void* d_out, int out_size, void* d_ws, size_t ws_size,
                              hipStream_t stream) {
    const float* x    = (const float*)d_in[0];
    const int*   esrc = (const int*)  d_in[1];
    const int*   edst = (const int*)  d_in[2];
    const float* eval = (const float*)d_in[3];
    const float* W1   = (const float*)d_in[4];
    const float* b1   = (const float*)d_in[5];
    const float* W2   = (const float*)d_in[6];
    const float* b2   = (const float*)d_in[7];
    float* out = (float*)d_out;

    const int N = in_sizes[0] / F;
    const int R = in_sizes[4] / (F * F);
    const int E = in_sizes[1] / R;
    const int RE = R * E;
    const int RN = R * N;
    const int nrb = (N + BM - 1) / BM;         // 391 for N=50000
    const int Mp = nrb * BM;
    const int nwg = nrb;                       // BN=256 covers all cols

    // ---- workspace layout ----
    char* ws = (char*)d_ws;
    unsigned short* Y = (unsigned short*)ws;             // [Mp][1024] bf16
    ws += (size_t)Mp * KC * sizeof(unsigned short);
    unsigned short* xb = (unsigned short*)ws;            // [N][256] bf16
    ws += (size_t)N * F * sizeof(unsigned short);
    unsigned short* x1b = (unsigned short*)ws;           // [N][256] bf16
    ws += (size_t)N * F * sizeof(unsigned short);
    unsigned short* WTc1 = (unsigned short*)ws;          // [256][1024] bf16
    ws += (size_t)F * KC * sizeof(unsigned short);
    unsigned short* WTc2 = (unsigned short*)ws;
    ws += (size_t)F * KC * sizeof(unsigned short);
    unsigned* epack = (unsigned*)ws;                     // [R*E] 4B packed
    ws += (size_t)RE * sizeof(unsigned);
    int* row_ptr = (int*)ws;                             // [R*N + 1]
    ws += (size_t)(RN + 1) * sizeof(int);
    int* cursor = (int*)ws;                              // [R*N]
    ws += (size_t)RN * sizeof(int);
    int* bsum = (int*)ws;

    // ---- CSR build (once; reused by both layers) ----
    hipMemsetAsync(row_ptr, 0, (size_t)(RN + 1) * sizeof(int), stream);
    count_kern<<<(RE + 255) / 256, 256, 0, stream>>>(edst, row_ptr, RE, E, N);
    const int nb_scan = (RN + SCAN_ELEMS - 1) / SCAN_ELEMS;
    scan1_kern<<<nb_scan, SCAN_T, 0, stream>>>(row_ptr, bsum, RN);
    scan2_kern<<<1, SCAN_T, 0, stream>>>(bsum, nb_scan);
    scan3_kern<<<(RN + 1 + 255) / 256, 256, 0, stream>>>(row_ptr, bsum, cursor, RN, RE);
    fill_kern<<<(RE + 255) / 256, 256, 0, stream>>>(esrc, edst, eval, cursor, epack, RE, E, N);

    // ---- weight transpose+convert (one merged launch) ----
    dim3 tgrid(F / 32, F / 32, 2 * R);
    transpose_wcat2<<<tgrid, 256, 0, stream>>>(W1, W2, WTc1, WTc2, R);

    // ---- input conversion (once) ----
    convert_bf16<<<(N * (F / 8) + 255) / 256, 256, 0, stream>>>(x, xb, N * (F / 8));

    // layer 1: Y = gather(xb); out/x1b = relu(Y @ Wc1 + b1)
    aggregate_g<<<N, 256, 0, stream>>>(xb, row_ptr, epack, Y, N);
    gemm_fused<false><<<nwg, 512, 0, stream>>>(Y, WTc1, b1, out, x1b, N, nwg);

    // layer 2: Y = gather(x1b); out = relu(Y @ Wc2 + b2) + out
    aggregate_g<<<N, 256, 0, stream>>>(x1b, row_ptr, epack, Y, N);
    gemm_fused<true><<<nwg, 512, 0, stream>>>(Y, WTc2, b2, out, x1b, N, nwg);
}